// Round 1
// baseline (421.825 us; speedup 1.0000x reference)
//
#include <hip/hip_runtime.h>
#include <math.h>

// Problem constants (from reference)
#define BPB 8              // bins per block in table build
static const int LBINS = 4096;

// ---------------- spherical harmonics l=0..3 (component norm, unit input) ----------------
__device__ __forceinline__ void sph_l3(float x, float y, float z, float* sh) {
    const float s3   = 1.7320508075688772f;
    const float s5   = 2.23606797749979f;
    const float s7   = 2.6457513110645906f;
    const float s15  = 3.872983346207417f;
    const float s105 = 10.246950765959598f;
    const float c358 = 2.0916500663351889f;  // sqrt(35/8)
    const float c218 = 1.6201851746019651f;  // sqrt(21/8)
    float x2 = x * x, y2 = y * y, z2 = z * z;
    sh[0]  = 1.0f;
    sh[1]  = s3 * x;
    sh[2]  = s3 * y;
    sh[3]  = s3 * z;
    sh[4]  = s15 * x * z;
    sh[5]  = s15 * x * y;
    sh[6]  = 0.5f * s5 * (2.0f * y2 - x2 - z2);
    sh[7]  = s15 * y * z;
    sh[8]  = 0.5f * s15 * (z2 - x2);
    sh[9]  = c358 * x * (3.0f * z2 - x2);
    sh[10] = s105 * x * y * z;
    sh[11] = c218 * x * (4.0f * y2 - z2 - x2);
    sh[12] = 0.5f * s7 * y * (2.0f * y2 - 3.0f * z2 - 3.0f * x2);
    sh[13] = c218 * z * (4.0f * y2 - z2 - x2);
    sh[14] = 0.5f * s105 * y * (z2 - x2);
    sh[15] = c358 * z * (z2 - 3.0f * x2);
}

// ---------------- K0: build weight tables T[lbins][448] = {w1[384], w2[64]}(len) ----------
__global__ void k_table(const float* __restrict__ W1a, const float* __restrict__ W1b,
                        const float* __restrict__ W2a, const float* __restrict__ W2b,
                        float* __restrict__ T, int lbins) {
    __shared__ float h1s[BPB][256];
    __shared__ float h2s[BPB][256];
    const int c = threadIdx.x;
    const int bin0 = blockIdx.x * BPB;
    const float inv_s3 = 0.57735026918962576f;
    const float bin2len = 4.0f / (float)(lbins - 1);
    float w1a0 = W1a[c], w1a1 = W1a[256 + c], w1a2 = W1a[512 + c];
    float w2a0 = W2a[c], w2a1 = W2a[256 + c], w2a2 = W2a[512 + c];
    for (int b = 0; b < BPB; ++b) {
        float len = (float)(bin0 + b) * bin2len;
        float d0 = len * 0.5f;
        float d1 = (len - 2.0f) * 0.5f;
        float d2 = (len - 4.0f) * 0.5f;
        float b0 = expf(-d0 * d0) * (1.0f / 1.12f);
        float b1 = expf(-d1 * d1) * (1.0f / 1.12f);
        float b2 = expf(-d2 * d2) * (1.0f / 1.12f);
        float z1 = (b0 * w1a0 + b1 * w1a1 + b2 * w1a2) * inv_s3;
        float z2 = (b0 * w2a0 + b1 * w2a1 + b2 * w2a2) * inv_s3;
        h1s[b][c] = fmaxf(z1, 0.0f);
        h2s[b][c] = fmaxf(z2, 0.0f);
    }
    __syncthreads();
    for (int o = threadIdx.x; o < 448; o += 256) {
        float acc[BPB];
#pragma unroll
        for (int b = 0; b < BPB; ++b) acc[b] = 0.0f;
        if (o < 384) {
            for (int cc = 0; cc < 256; ++cc) {
                float w = W1b[cc * 384 + o];
#pragma unroll
                for (int b = 0; b < BPB; ++b) acc[b] += h1s[b][cc] * w;
            }
        } else {
            int k = o - 384;
            for (int cc = 0; cc < 256; ++cc) {
                float w = W2b[cc * 64 + k];
#pragma unroll
                for (int b = 0; b < BPB; ++b) acc[b] += h2s[b][cc] * w;
            }
        }
#pragma unroll
        for (int b = 0; b < BPB; ++b)
            T[(size_t)(bin0 + b) * 448 + o] = acc[b] * (1.0f / 16.0f);
    }
}

// ---------------- K1: x_raw[dst] += sh(edge)  (thread per edge) --------------------------
__global__ void k_edge_sh(const float* __restrict__ evec, const int* __restrict__ edst,
                          float* __restrict__ x_raw, int E) {
    int e = blockIdx.x * blockDim.x + threadIdx.x;
    if (e >= E) return;
    float vx = evec[3 * e], vy = evec[3 * e + 1], vz = evec[3 * e + 2];
    float nrm = sqrtf(vx * vx + vy * vy + vz * vz);
    float inv = 1.0f / (nrm + 1e-12f);
    float sh[16];
    sph_l3(vx * inv, vy * inv, vz * inv, sh);
    int d = edst[e];
    float* p = x_raw + (size_t)d * 16;
#pragma unroll
    for (int j = 0; j < 16; ++j) atomicAdd(p + j, sh[j]);
}

// ---------------- K2: h_node[dst][k] += 0.5*inv_nn * sum_p dots[p]*w1(len)[p][k] ----------
// one wave per edge; lanes cover k = 0..95 (two strided iterations)
__global__ void k_edge_main(const float* __restrict__ evec, const float* __restrict__ elen,
                            const int* __restrict__ esrc, const int* __restrict__ edst,
                            const float* __restrict__ x_raw, const float* __restrict__ T,
                            float* __restrict__ h_node, int E, int lbins) {
    int wave = (blockIdx.x * blockDim.x + threadIdx.x) >> 6;
    int lane = threadIdx.x & 63;
    if (wave >= E) return;
    const int e = wave;
    const float inv_nn = 0.51298917604257706f;  // 1/sqrt(3.8)
    const float rs3 = 0.57735026918962576f;
    const float rs5 = 0.44721359549995793f;
    const float rs7 = 0.37796447300922720f;

    float vx = evec[3 * e], vy = evec[3 * e + 1], vz = evec[3 * e + 2];
    float nrm = sqrtf(vx * vx + vy * vy + vz * vz);
    float inv = 1.0f / (nrm + 1e-12f);
    float sh[16];
    sph_l3(vx * inv, vy * inv, vz * inv, sh);

    int src = esrc[e], dst = edst[e];
    const float* xr = x_raw + (size_t)src * 16;
    float d0 = xr[0] * sh[0];
    float d1 = xr[1] * sh[1] + xr[2] * sh[2] + xr[3] * sh[3];
    float d2 = 0.0f;
#pragma unroll
    for (int i = 4; i < 9; ++i) d2 += xr[i] * sh[i];
    float d3 = 0.0f;
#pragma unroll
    for (int i = 9; i < 16; ++i) d3 += xr[i] * sh[i];
    float dots[4];
    dots[0] = d0 * inv_nn;
    dots[1] = d1 * inv_nn * rs3;
    dots[2] = d2 * inv_nn * rs5;
    dots[3] = d3 * inv_nn * rs7;

    float len = elen[e];
    float pos = fminf(fmaxf(len, 0.0f), 4.0f) * ((float)(lbins - 1) / 4.0f);
    int i0 = (int)pos;
    if (i0 > lbins - 2) i0 = lbins - 2;
    float f = pos - (float)i0;
    const float* r0 = T + (size_t)i0 * 448;
    const float* r1 = r0 + 448;

    const float scale = 0.5f * inv_nn;
    float* hn = h_node + (size_t)dst * 96;
    for (int kk = lane; kk < 96; kk += 64) {
        float acc = 0.0f;
#pragma unroll
        for (int p = 0; p < 4; ++p) {
            float w0 = r0[p * 96 + kk];
            float w1 = r1[p * 96 + kk];
            acc += dots[p] * (w0 + f * (w1 - w0));
        }
        atomicAdd(hn + kk, acc * scale);
    }
}

// ---------------- K3: node activations y[N,64] from h_node[N,96] --------------------------
__global__ void k_node_y(const float* __restrict__ h_node, float* __restrict__ y, int N) {
    int t = blockIdx.x * blockDim.x + threadIdx.x;
    if (t >= N * 64) return;
    int n = t >> 6, k = t & 63;
    const float* h = h_node + (size_t)n * 96;
    float out;
    if (k < 32) {
        float v = h[k];
        out = (k < 16) ? fmaxf(v, 0.0f) : fabsf(v);
    } else {
        int kg = k - 32;
        float g = h[32 + kg];
        float vv = h[64 + kg];
        float ga;
        if (kg < 8) ga = fmaxf(g, 0.0f);
        else if (kg < 16) ga = tanhf(g);
        else if (kg < 24) ga = fmaxf(g, 0.0f);
        else ga = tanhf(g);
        out = ga * vv;
    }
    y[t] = out;
}

// ---------------- K4: out[dst] += (inv_nn/8) * sum_k y[src][k]*w2(len)[k] ------------------
// one wave per edge; lane k = 0..63; shfl reduce; 1 atomic per edge
__global__ void k_edge_out(const float* __restrict__ elen, const int* __restrict__ esrc,
                           const int* __restrict__ edst, const float* __restrict__ y,
                           const float* __restrict__ T, float* __restrict__ out,
                           int E, int lbins) {
    int wave = (blockIdx.x * blockDim.x + threadIdx.x) >> 6;
    int lane = threadIdx.x & 63;
    if (wave >= E) return;
    const int e = wave;
    float len = elen[e];
    int src = esrc[e], dst = edst[e];
    float pos = fminf(fmaxf(len, 0.0f), 4.0f) * ((float)(lbins - 1) / 4.0f);
    int i0 = (int)pos;
    if (i0 > lbins - 2) i0 = lbins - 2;
    float f = pos - (float)i0;
    float w0 = T[(size_t)i0 * 448 + 384 + lane];
    float w1 = T[(size_t)(i0 + 1) * 448 + 384 + lane];
    float w2v = w0 + f * (w1 - w0);
    float t = y[(size_t)src * 64 + lane] * w2v;
#pragma unroll
    for (int off = 32; off > 0; off >>= 1) t += __shfl_xor(t, off, 64);
    if (lane == 0) {
        const float c = 0.51298917604257706f / 8.0f;  // inv_nn / 8
        atomicAdd(out + dst, t * c);
    }
}

extern "C" void kernel_launch(void* const* d_in, const int* in_sizes, int n_in,
                              void* d_out, int out_size, void* d_ws, size_t ws_size,
                              hipStream_t stream) {
    const float* evec = (const float*)d_in[0];
    const float* elen = (const float*)d_in[1];
    const float* W1a  = (const float*)d_in[2];
    const float* W1b  = (const float*)d_in[3];
    const float* W2a  = (const float*)d_in[4];
    const float* W2b  = (const float*)d_in[5];
    const int* esrc   = (const int*)d_in[6];
    const int* edst   = (const int*)d_in[7];
    const int E = in_sizes[1];
    const int N = out_size;
    float* out = (float*)d_out;

    // workspace layout
    char* ws = (char*)d_ws;
    size_t off = 0;
    auto alloc = [&](size_t bytes) -> void* {
        void* p = ws + off;
        off = (off + bytes + 255) & ~(size_t)255;
        return p;
    };
    // choose lbins to fit workspace (fixed parts first)
    size_t fixed = ((size_t)N * 16 * 4 + 256) + ((size_t)N * 96 * 4 + 256) + ((size_t)N * 64 * 4 + 256);
    int lbins = LBINS;
    if (ws_size > fixed) {
        size_t avail = ws_size - fixed;
        size_t maxbins = avail / (448 * 4);
        if ((size_t)lbins > maxbins) lbins = (int)((maxbins / BPB) * BPB);
    }
    if (lbins < 2 * BPB) lbins = 2 * BPB;  // last resort; assumes ws is big enough

    float* T      = (float*)alloc((size_t)lbins * 448 * 4);
    float* x_raw  = (float*)alloc((size_t)N * 16 * 4);
    float* h_node = (float*)alloc((size_t)N * 96 * 4);
    float* y      = (float*)alloc((size_t)N * 64 * 4);

    hipMemsetAsync(x_raw, 0, (size_t)N * 16 * 4, stream);
    hipMemsetAsync(h_node, 0, (size_t)N * 96 * 4, stream);
    hipMemsetAsync(out, 0, (size_t)N * 4, stream);

    k_table<<<lbins / BPB, 256, 0, stream>>>(W1a, W1b, W2a, W2b, T, lbins);
    k_edge_sh<<<(E + 255) / 256, 256, 0, stream>>>(evec, edst, x_raw, E);
    {
        long long threads = (long long)E * 64;
        int blocks = (int)((threads + 255) / 256);
        k_edge_main<<<blocks, 256, 0, stream>>>(evec, elen, esrc, edst, x_raw, T, h_node, E, lbins);
    }
    k_node_y<<<(N * 64 + 255) / 256, 256, 0, stream>>>(h_node, y, N);
    {
        long long threads = (long long)E * 64;
        int blocks = (int)((threads + 255) / 256);
        k_edge_out<<<blocks, 256, 0, stream>>>(elen, esrc, edst, y, T, out, E, lbins);
    }
}

// Round 3
// 246.193 us; speedup vs baseline: 1.7134x; 1.7134x over previous
//
#include <hip/hip_runtime.h>
#include <math.h>

#define BPB 8              // bins per block in table build
static const int LBINS = 4096;

// ---------------- spherical harmonics l=0..3 (component norm, unit input) ----------------
__device__ __forceinline__ void sph_l3(float x, float y, float z, float* sh) {
    const float s3   = 1.7320508075688772f;
    const float s5   = 2.23606797749979f;
    const float s7   = 2.6457513110645906f;
    const float s15  = 3.872983346207417f;
    const float s105 = 10.246950765959598f;
    const float c358 = 2.0916500663351889f;  // sqrt(35/8)
    const float c218 = 1.6201851746019651f;  // sqrt(21/8)
    float x2 = x * x, y2 = y * y, z2 = z * z;
    sh[0]  = 1.0f;
    sh[1]  = s3 * x;
    sh[2]  = s3 * y;
    sh[3]  = s3 * z;
    sh[4]  = s15 * x * z;
    sh[5]  = s15 * x * y;
    sh[6]  = 0.5f * s5 * (2.0f * y2 - x2 - z2);
    sh[7]  = s15 * y * z;
    sh[8]  = 0.5f * s15 * (z2 - x2);
    sh[9]  = c358 * x * (3.0f * z2 - x2);
    sh[10] = s105 * x * y * z;
    sh[11] = c218 * x * (4.0f * y2 - z2 - x2);
    sh[12] = 0.5f * s7 * y * (2.0f * y2 - 3.0f * z2 - 3.0f * x2);
    sh[13] = c218 * z * (4.0f * y2 - z2 - x2);
    sh[14] = 0.5f * s105 * y * (z2 - x2);
    sh[15] = c358 * z * (z2 - 3.0f * x2);
}

// ---------------- K0: build weight tables T[lbins][448] = {w1[384]/16, w2[64]/16}(len) ----
__global__ void k_table(const float* __restrict__ W1a, const float* __restrict__ W1b,
                        const float* __restrict__ W2a, const float* __restrict__ W2b,
                        float* __restrict__ T, int lbins) {
    __shared__ float h1s[BPB][256];
    __shared__ float h2s[BPB][256];
    const int c = threadIdx.x;
    const int bin0 = blockIdx.x * BPB;
    const float inv_s3 = 0.57735026918962576f;
    const float bin2len = 4.0f / (float)(lbins - 1);
    float w1a0 = W1a[c], w1a1 = W1a[256 + c], w1a2 = W1a[512 + c];
    float w2a0 = W2a[c], w2a1 = W2a[256 + c], w2a2 = W2a[512 + c];
    for (int b = 0; b < BPB; ++b) {
        float len = (float)(bin0 + b) * bin2len;
        float d0 = len * 0.5f;
        float d1 = (len - 2.0f) * 0.5f;
        float d2 = (len - 4.0f) * 0.5f;
        float b0 = expf(-d0 * d0) * (1.0f / 1.12f);
        float b1 = expf(-d1 * d1) * (1.0f / 1.12f);
        float b2 = expf(-d2 * d2) * (1.0f / 1.12f);
        float z1 = (b0 * w1a0 + b1 * w1a1 + b2 * w1a2) * inv_s3;
        float z2 = (b0 * w2a0 + b1 * w2a1 + b2 * w2a2) * inv_s3;
        h1s[b][c] = fmaxf(z1, 0.0f);
        h2s[b][c] = fmaxf(z2, 0.0f);
    }
    __syncthreads();
    for (int o = threadIdx.x; o < 448; o += 256) {
        float acc[BPB];
#pragma unroll
        for (int b = 0; b < BPB; ++b) acc[b] = 0.0f;
        if (o < 384) {
            for (int cc = 0; cc < 256; ++cc) {
                float w = W1b[cc * 384 + o];
#pragma unroll
                for (int b = 0; b < BPB; ++b) acc[b] += h1s[b][cc] * w;
            }
        } else {
            int k = o - 384;
            for (int cc = 0; cc < 256; ++cc) {
                float w = W2b[cc * 64 + k];
#pragma unroll
                for (int b = 0; b < BPB; ++b) acc[b] += h2s[b][cc] * w;
            }
        }
#pragma unroll
        for (int b = 0; b < BPB; ++b)
            T[(size_t)(bin0 + b) * 448 + o] = acc[b] * (1.0f / 16.0f);
    }
}

// ---------------- CSR build: hist -> scan -> scatter --------------------------------------
__global__ void k_hist(const int* __restrict__ edst, int* __restrict__ deg, int E) {
    int e = blockIdx.x * blockDim.x + threadIdx.x;
    if (e < E) atomicAdd(&deg[edst[e]], 1);
}

__global__ void k_scan(const int* __restrict__ deg, int* __restrict__ rowptr, int N) {
    __shared__ int part[1024];
    int t = threadIdx.x;
    int chunk = (N + 1023) >> 10;
    int s = t * chunk;
    int epos = s + chunk; if (epos > N) epos = N;
    int sum = 0;
    for (int i = s; i < epos; ++i) sum += deg[i];
    part[t] = sum;
    __syncthreads();
    // Hillis-Steele inclusive scan over 1024 partials
    for (int off = 1; off < 1024; off <<= 1) {
        int v = (t >= off) ? part[t - off] : 0;
        __syncthreads();
        part[t] += v;
        __syncthreads();
    }
    int run = (t == 0) ? 0 : part[t - 1];
    for (int i = s; i < epos; ++i) { rowptr[i] = run; run += deg[i]; }
    // exactly ONE thread writes the sentinel: total = inclusive scan of last partial
    if (t == 1023) rowptr[N] = part[1023];
}

__global__ void k_scatter(const int* __restrict__ edst, const int* __restrict__ rowptr,
                          int* __restrict__ cursor, int* __restrict__ perm, int E) {
    int e = blockIdx.x * blockDim.x + threadIdx.x;
    if (e >= E) return;
    int d = edst[e];
    int pos = rowptr[d] + atomicAdd(&cursor[d], 1);
    perm[pos] = e;
}

// ---------------- K4: x[n][16] = inv_nn * sum_{e in in(n)} sh(e)   (thread per node) ------
__global__ void k_x(const float* __restrict__ evec, const int* __restrict__ perm,
                    const int* __restrict__ rowptr, float* __restrict__ x, int N) {
    int n = blockIdx.x * blockDim.x + threadIdx.x;
    if (n >= N) return;
    float acc[16];
#pragma unroll
    for (int i = 0; i < 16; ++i) acc[i] = 0.0f;
    int r0 = rowptr[n], r1 = rowptr[n + 1];
    for (int j = r0; j < r1; ++j) {
        int e = perm[j];
        float vx = evec[3 * e], vy = evec[3 * e + 1], vz = evec[3 * e + 2];
        float nrm = sqrtf(vx * vx + vy * vy + vz * vz);
        float inv = 1.0f / (nrm + 1e-12f);
        float sh[16];
        sph_l3(vx * inv, vy * inv, vz * inv, sh);
#pragma unroll
        for (int i = 0; i < 16; ++i) acc[i] += sh[i];
    }
    const float inv_nn = 0.51298917604257706f;  // 1/sqrt(3.8)
    float* xp = x + (size_t)n * 16;
#pragma unroll
    for (int i = 0; i < 16; ++i) xp[i] = acc[i] * inv_nn;
}

// ---------------- K5: per-edge dots[4] + lerp coords  (thread per edge) --------------------
__global__ void k_dots(const float* __restrict__ evec, const float* __restrict__ elen,
                       const int* __restrict__ esrc, const float* __restrict__ x,
                       float4* __restrict__ dots4, int* __restrict__ lerpi,
                       float* __restrict__ lerpf, int E, int lbins) {
    int e = blockIdx.x * blockDim.x + threadIdx.x;
    if (e >= E) return;
    float vx = evec[3 * e], vy = evec[3 * e + 1], vz = evec[3 * e + 2];
    float nrm = sqrtf(vx * vx + vy * vy + vz * vz);
    float inv = 1.0f / (nrm + 1e-12f);
    float sh[16];
    sph_l3(vx * inv, vy * inv, vz * inv, sh);
    const float* xr = x + (size_t)esrc[e] * 16;
    float d0 = xr[0] * sh[0];
    float d1 = xr[1] * sh[1] + xr[2] * sh[2] + xr[3] * sh[3];
    float d2 = 0.0f;
#pragma unroll
    for (int i = 4; i < 9; ++i) d2 += xr[i] * sh[i];
    float d3 = 0.0f;
#pragma unroll
    for (int i = 9; i < 16; ++i) d3 += xr[i] * sh[i];
    const float rs3 = 0.57735026918962576f;
    const float rs5 = 0.44721359549995793f;
    const float rs7 = 0.37796447300922720f;
    dots4[e] = make_float4(d0, d1 * rs3, d2 * rs5, d3 * rs7);
    float len = elen[e];
    float pos = fminf(fmaxf(len, 0.0f), 4.0f) * ((float)(lbins - 1) / 4.0f);
    int i0 = (int)pos;
    if (i0 > lbins - 2) i0 = lbins - 2;
    lerpi[e] = i0;
    lerpf[e] = pos - (float)i0;
}

// ---------------- K6: per-node h[96] -> activations -> y[n][64]  (block 128 per node) ------
__global__ __launch_bounds__(128) void k_hy(const float4* __restrict__ dots4,
                                            const int* __restrict__ lerpi,
                                            const float* __restrict__ lerpf,
                                            const int* __restrict__ perm,
                                            const int* __restrict__ rowptr,
                                            const float* __restrict__ T,
                                            float* __restrict__ y, int N) {
    int n = blockIdx.x;
    if (n >= N) return;
    int kk = threadIdx.x;
    __shared__ float hs[96];
    int r0 = rowptr[n], r1 = rowptr[n + 1];
    if (kk < 96) {
        float acc = 0.0f;
        for (int j = r0; j < r1; ++j) {
            int e = perm[j];
            float4 dt = dots4[e];
            int i0 = lerpi[e];
            float f = lerpf[e];
            const float* tp = T + (size_t)i0 * 448 + kk;
            float a0 = tp[0],   b0 = tp[448];
            float a1 = tp[96],  b1 = tp[448 + 96];
            float a2 = tp[192], b2 = tp[448 + 192];
            float a3 = tp[288], b3 = tp[448 + 288];
            acc += dt.x * (a0 + f * (b0 - a0)) + dt.y * (a1 + f * (b1 - a1))
                 + dt.z * (a2 + f * (b2 - a2)) + dt.w * (a3 + f * (b3 - a3));
        }
        const float scale = 0.5f * 0.51298917604257706f;  // 0.5 * inv_nn
        hs[kk] = acc * scale;
    }
    __syncthreads();
    int t = threadIdx.x;
    if (t < 64) {
        float outv;
        if (t < 32) {
            float v = hs[t];
            outv = (t < 16) ? fmaxf(v, 0.0f) : fabsf(v);
        } else {
            int kg = t - 32;
            float g = hs[32 + kg];
            float vv = hs[64 + kg];
            float ga = (kg < 8 || (kg >= 16 && kg < 24)) ? fmaxf(g, 0.0f) : tanhf(g);
            outv = ga * vv;
        }
        y[(size_t)n * 64 + t] = outv;
    }
}

// ---------------- K7: out[n] = inv_nn/8 * sum_{e in in(n)} y[src]·w2(len)  (wave/node) -----
__global__ void k_out(const int* __restrict__ esrc, const int* __restrict__ lerpi,
                      const float* __restrict__ lerpf, const int* __restrict__ perm,
                      const int* __restrict__ rowptr, const float* __restrict__ y,
                      const float* __restrict__ T, float* __restrict__ out, int N) {
    int n = (blockIdx.x * blockDim.x + threadIdx.x) >> 6;
    int lane = threadIdx.x & 63;
    if (n >= N) return;
    int r0 = rowptr[n], r1 = rowptr[n + 1];
    float acc = 0.0f;
    for (int j = r0; j < r1; ++j) {
        int e = perm[j];
        int i0 = lerpi[e];
        float f = lerpf[e];
        const float* tp = T + (size_t)i0 * 448 + 384 + lane;
        float w0 = tp[0], w1 = tp[448];
        float w2v = w0 + f * (w1 - w0);
        acc += y[(size_t)esrc[e] * 64 + lane] * w2v;
    }
#pragma unroll
    for (int off = 32; off > 0; off >>= 1) acc += __shfl_xor(acc, off, 64);
    if (lane == 0) out[n] = acc * (0.51298917604257706f / 8.0f);
}

extern "C" void kernel_launch(void* const* d_in, const int* in_sizes, int n_in,
                              void* d_out, int out_size, void* d_ws, size_t ws_size,
                              hipStream_t stream) {
    const float* evec = (const float*)d_in[0];
    const float* elen = (const float*)d_in[1];
    const float* W1a  = (const float*)d_in[2];
    const float* W1b  = (const float*)d_in[3];
    const float* W2a  = (const float*)d_in[4];
    const float* W2b  = (const float*)d_in[5];
    const int* esrc   = (const int*)d_in[6];
    const int* edst   = (const int*)d_in[7];
    const int E = in_sizes[1];
    const int N = out_size;
    float* out = (float*)d_out;

    char* ws = (char*)d_ws;
    size_t off = 0;
    auto alloc = [&](size_t bytes) -> void* {
        void* p = ws + off;
        off = (off + bytes + 255) & ~(size_t)255;
        return p;
    };

    // fixed buffers first
    int*    deg    = (int*)alloc((size_t)N * 4);
    int*    cursor = (int*)alloc((size_t)N * 4);
    int*    rowptr = (int*)alloc((size_t)(N + 1) * 4);
    int*    perm   = (int*)alloc((size_t)E * 4);
    float*  x      = (float*)alloc((size_t)N * 16 * 4);
    float4* dots4  = (float4*)alloc((size_t)E * 16);
    int*    lerpi  = (int*)alloc((size_t)E * 4);
    float*  lerpf  = (float*)alloc((size_t)E * 4);
    float*  y      = (float*)alloc((size_t)N * 64 * 4);

    // adaptive table size with remaining workspace
    int lbins = LBINS;
    if (ws_size > off) {
        size_t avail = ws_size - off;
        size_t maxbins = avail / (448 * 4);
        if ((size_t)lbins > maxbins) lbins = (int)((maxbins / BPB) * BPB);
    }
    if (lbins < 2 * BPB) lbins = 2 * BPB;
    float* T = (float*)alloc((size_t)lbins * 448 * 4);

    hipMemsetAsync(deg, 0, (size_t)N * 4, stream);
    hipMemsetAsync(cursor, 0, (size_t)N * 4, stream);

    k_table<<<lbins / BPB, 256, 0, stream>>>(W1a, W1b, W2a, W2b, T, lbins);
    k_hist<<<(E + 255) / 256, 256, 0, stream>>>(edst, deg, E);
    k_scan<<<1, 1024, 0, stream>>>(deg, rowptr, N);
    k_scatter<<<(E + 255) / 256, 256, 0, stream>>>(edst, rowptr, cursor, perm, E);
    k_x<<<(N + 255) / 256, 256, 0, stream>>>(evec, perm, rowptr, x, N);
    k_dots<<<(E + 255) / 256, 256, 0, stream>>>(evec, elen, esrc, x, dots4, lerpi, lerpf, E, lbins);
    k_hy<<<N, 128, 0, stream>>>(dots4, lerpi, lerpf, perm, rowptr, T, y, N);
    {
        long long threads = (long long)N * 64;
        int blocks = (int)((threads + 255) / 256);
        k_out<<<blocks, 256, 0, stream>>>(esrc, lerpi, lerpf, perm, rowptr, y, T, out, N);
    }
}

// Round 4
// 209.878 us; speedup vs baseline: 2.0099x; 1.1730x over previous
//
#include <hip/hip_runtime.h>
#include <math.h>

#define BPB 8              // bins per block in table build
static const int LBINS = 2048;   // 2048*448*4 = 3.67 MB -> fits 4 MB per-XCD L2

// ---------------- spherical harmonics l=0..3 (component norm, unit input) ----------------
__device__ __forceinline__ void sph_l3(float x, float y, float z, float* sh) {
    const float s3   = 1.7320508075688772f;
    const float s5   = 2.23606797749979f;
    const float s7   = 2.6457513110645906f;
    const float s15  = 3.872983346207417f;
    const float s105 = 10.246950765959598f;
    const float c358 = 2.0916500663351889f;  // sqrt(35/8)
    const float c218 = 1.6201851746019651f;  // sqrt(21/8)
    float x2 = x * x, y2 = y * y, z2 = z * z;
    sh[0]  = 1.0f;
    sh[1]  = s3 * x;
    sh[2]  = s3 * y;
    sh[3]  = s3 * z;
    sh[4]  = s15 * x * z;
    sh[5]  = s15 * x * y;
    sh[6]  = 0.5f * s5 * (2.0f * y2 - x2 - z2);
    sh[7]  = s15 * y * z;
    sh[8]  = 0.5f * s15 * (z2 - x2);
    sh[9]  = c358 * x * (3.0f * z2 - x2);
    sh[10] = s105 * x * y * z;
    sh[11] = c218 * x * (4.0f * y2 - z2 - x2);
    sh[12] = 0.5f * s7 * y * (2.0f * y2 - 3.0f * z2 - 3.0f * x2);
    sh[13] = c218 * z * (4.0f * y2 - z2 - x2);
    sh[14] = 0.5f * s105 * y * (z2 - x2);
    sh[15] = c358 * z * (z2 - 3.0f * x2);
}

// ---------------- K0: build weight tables T[lbins][448] = {w1[384]/16, w2[64]/16}(len) ----
__global__ void k_table(const float* __restrict__ W1a, const float* __restrict__ W1b,
                        const float* __restrict__ W2a, const float* __restrict__ W2b,
                        float* __restrict__ T, int lbins) {
    __shared__ float h1s[BPB][256];
    __shared__ float h2s[BPB][256];
    const int c = threadIdx.x;
    const int bin0 = blockIdx.x * BPB;
    const float inv_s3 = 0.57735026918962576f;
    const float bin2len = 4.0f / (float)(lbins - 1);
    float w1a0 = W1a[c], w1a1 = W1a[256 + c], w1a2 = W1a[512 + c];
    float w2a0 = W2a[c], w2a1 = W2a[256 + c], w2a2 = W2a[512 + c];
    for (int b = 0; b < BPB; ++b) {
        float len = (float)(bin0 + b) * bin2len;
        float d0 = len * 0.5f;
        float d1 = (len - 2.0f) * 0.5f;
        float d2 = (len - 4.0f) * 0.5f;
        float b0 = expf(-d0 * d0) * (1.0f / 1.12f);
        float b1 = expf(-d1 * d1) * (1.0f / 1.12f);
        float b2 = expf(-d2 * d2) * (1.0f / 1.12f);
        float z1 = (b0 * w1a0 + b1 * w1a1 + b2 * w1a2) * inv_s3;
        float z2 = (b0 * w2a0 + b1 * w2a1 + b2 * w2a2) * inv_s3;
        h1s[b][c] = fmaxf(z1, 0.0f);
        h2s[b][c] = fmaxf(z2, 0.0f);
    }
    __syncthreads();
    for (int o = threadIdx.x; o < 448; o += 256) {
        float acc[BPB];
#pragma unroll
        for (int b = 0; b < BPB; ++b) acc[b] = 0.0f;
        if (o < 384) {
            for (int cc = 0; cc < 256; ++cc) {
                float w = W1b[cc * 384 + o];
#pragma unroll
                for (int b = 0; b < BPB; ++b) acc[b] += h1s[b][cc] * w;
            }
        } else {
            int k = o - 384;
            for (int cc = 0; cc < 256; ++cc) {
                float w = W2b[cc * 64 + k];
#pragma unroll
                for (int b = 0; b < BPB; ++b) acc[b] += h2s[b][cc] * w;
            }
        }
#pragma unroll
        for (int b = 0; b < BPB; ++b)
            T[(size_t)(bin0 + b) * 448 + o] = acc[b] * (1.0f / 16.0f);
    }
}

// ---------------- CSR build ----------------------------------------------------------------
__global__ void k_hist(const int* __restrict__ edst, int* __restrict__ deg, int E) {
    int e = blockIdx.x * blockDim.x + threadIdx.x;
    if (e < E) atomicAdd(&deg[edst[e]], 1);
}

__global__ void k_scan(const int* __restrict__ deg, int* __restrict__ rowptr, int N) {
    __shared__ int part[1024];
    int t = threadIdx.x;
    int chunk = (N + 1023) >> 10;
    int s = t * chunk;
    int epos = s + chunk; if (epos > N) epos = N;
    int sum = 0;
    for (int i = s; i < epos; ++i) sum += deg[i];
    part[t] = sum;
    __syncthreads();
    for (int off = 1; off < 1024; off <<= 1) {
        int v = (t >= off) ? part[t - off] : 0;
        __syncthreads();
        part[t] += v;
        __syncthreads();
    }
    int run = (t == 0) ? 0 : part[t - 1];
    for (int i = s; i < epos; ++i) { rowptr[i] = run; run += deg[i]; }
    if (t == 1023) rowptr[N] = part[1023];
}

// ---------------- K3: scatter edges into perm order, materializing everything ---------------
// writes (perm-ordered): shP[pos][16], srcP[pos], lerpP[pos]={(float)i0, f}
__global__ void k_scatter(const float* __restrict__ evec, const float* __restrict__ elen,
                          const int* __restrict__ esrc, const int* __restrict__ edst,
                          int* __restrict__ cursor,   // preloaded copy of rowptr
                          float4* __restrict__ shP4, int* __restrict__ srcP,
                          float2* __restrict__ lerpP, int E, int lbins) {
    int e = blockIdx.x * blockDim.x + threadIdx.x;
    if (e >= E) return;
    int d = edst[e];
    int pos = atomicAdd(&cursor[d], 1);

    float vx = evec[3 * e], vy = evec[3 * e + 1], vz = evec[3 * e + 2];
    float nrm = sqrtf(vx * vx + vy * vy + vz * vz);
    float inv = 1.0f / (nrm + 1e-12f);
    float sh[16];
    sph_l3(vx * inv, vy * inv, vz * inv, sh);
    float4* sp = shP4 + (size_t)pos * 4;
    sp[0] = make_float4(sh[0], sh[1], sh[2], sh[3]);
    sp[1] = make_float4(sh[4], sh[5], sh[6], sh[7]);
    sp[2] = make_float4(sh[8], sh[9], sh[10], sh[11]);
    sp[3] = make_float4(sh[12], sh[13], sh[14], sh[15]);
    srcP[pos] = esrc[e];

    float len = elen[e];
    float p = fminf(fmaxf(len, 0.0f), 4.0f) * ((float)(lbins - 1) / 4.0f);
    int i0 = (int)p;
    if (i0 > lbins - 2) i0 = lbins - 2;
    lerpP[pos] = make_float2((float)i0, p - (float)i0);
}

// ---------------- K4: x[n][16] = inv_nn * sum rows of shP   (thread per node, seq reads) ----
__global__ void k_x(const float4* __restrict__ shP4, const int* __restrict__ rowptr,
                    float4* __restrict__ x4, int N) {
    int n = blockIdx.x * blockDim.x + threadIdx.x;
    if (n >= N) return;
    float4 a0 = make_float4(0, 0, 0, 0), a1 = a0, a2 = a0, a3 = a0;
    int r0 = rowptr[n], r1 = rowptr[n + 1];
    for (int j = r0; j < r1; ++j) {
        const float4* sp = shP4 + (size_t)j * 4;
        float4 s0 = sp[0], s1 = sp[1], s2 = sp[2], s3 = sp[3];
        a0.x += s0.x; a0.y += s0.y; a0.z += s0.z; a0.w += s0.w;
        a1.x += s1.x; a1.y += s1.y; a1.z += s1.z; a1.w += s1.w;
        a2.x += s2.x; a2.y += s2.y; a2.z += s2.z; a2.w += s2.w;
        a3.x += s3.x; a3.y += s3.y; a3.z += s3.z; a3.w += s3.w;
    }
    const float inv_nn = 0.51298917604257706f;
    float4* xp = x4 + (size_t)n * 4;
    xp[0] = make_float4(a0.x * inv_nn, a0.y * inv_nn, a0.z * inv_nn, a0.w * inv_nn);
    xp[1] = make_float4(a1.x * inv_nn, a1.y * inv_nn, a1.z * inv_nn, a1.w * inv_nn);
    xp[2] = make_float4(a2.x * inv_nn, a2.y * inv_nn, a2.z * inv_nn, a2.w * inv_nn);
    xp[3] = make_float4(a3.x * inv_nn, a3.y * inv_nn, a3.z * inv_nn, a3.w * inv_nn);
}

// ---------------- K5: dotsP[j] (thread per perm-slot; seq shP read, 1-hop x gather) ---------
__global__ void k_dots(const float4* __restrict__ shP4, const int* __restrict__ srcP,
                       const float4* __restrict__ x4, float4* __restrict__ dotsP, int E) {
    int j = blockIdx.x * blockDim.x + threadIdx.x;
    if (j >= E) return;
    const float4* sp = shP4 + (size_t)j * 4;
    float4 s0 = sp[0], s1 = sp[1], s2 = sp[2], s3 = sp[3];
    const float4* xr = x4 + (size_t)srcP[j] * 4;
    float4 x0 = xr[0], x1 = xr[1], x2 = xr[2], x3 = xr[3];
    float d0 = x0.x * s0.x;
    float d1 = x0.y * s0.y + x0.z * s0.z + x0.w * s0.w;
    float d2 = x1.x * s1.x + x1.y * s1.y + x1.z * s1.z + x1.w * s1.w + x2.x * s2.x;
    float d3 = x2.y * s2.y + x2.z * s2.z + x2.w * s2.w
             + x3.x * s3.x + x3.y * s3.y + x3.z * s3.z + x3.w * s3.w;
    const float rs3 = 0.57735026918962576f;
    const float rs5 = 0.44721359549995793f;
    const float rs7 = 0.37796447300922720f;
    dotsP[j] = make_float4(d0, d1 * rs3, d2 * rs5, d3 * rs7);
}

// ---------------- K6: per-node h[96] -> activations -> y[n][64]  (block 128 per node) ------
__global__ __launch_bounds__(128) void k_hy(const float4* __restrict__ dotsP,
                                            const float2* __restrict__ lerpP,
                                            const int* __restrict__ rowptr,
                                            const float* __restrict__ T,
                                            float* __restrict__ y, int N) {
    int n = blockIdx.x;
    if (n >= N) return;
    int kk = threadIdx.x;
    __shared__ float hs[96];
    int r0 = rowptr[n], r1 = rowptr[n + 1];
    if (kk < 96) {
        float acc = 0.0f;
        for (int j = r0; j < r1; ++j) {
            float4 dt = dotsP[j];
            float2 lp = lerpP[j];
            int i0 = (int)lp.x;
            float f = lp.y;
            const float* tp = T + (size_t)i0 * 448 + kk;
            float a0 = tp[0],   b0 = tp[448];
            float a1 = tp[96],  b1 = tp[448 + 96];
            float a2 = tp[192], b2 = tp[448 + 192];
            float a3 = tp[288], b3 = tp[448 + 288];
            acc += dt.x * (a0 + f * (b0 - a0)) + dt.y * (a1 + f * (b1 - a1))
                 + dt.z * (a2 + f * (b2 - a2)) + dt.w * (a3 + f * (b3 - a3));
        }
        const float scale = 0.25649458802128853f;  // 0.5 * inv_nn
        hs[kk] = acc * scale;
    }
    __syncthreads();
    int t = threadIdx.x;
    if (t < 64) {
        float outv;
        if (t < 32) {
            float v = hs[t];
            outv = (t < 16) ? fmaxf(v, 0.0f) : fabsf(v);
        } else {
            int kg = t - 32;
            float g = hs[32 + kg];
            float vv = hs[64 + kg];
            float ga = (kg < 8 || (kg >= 16 && kg < 24)) ? fmaxf(g, 0.0f) : tanhf(g);
            outv = ga * vv;
        }
        y[(size_t)n * 64 + t] = outv;
    }
}

// ---------------- K7: out[n] = inv_nn/8 * sum_j y[srcP[j]]·w2(lerpP[j])  (wave/node) --------
__global__ void k_out(const int* __restrict__ srcP, const float2* __restrict__ lerpP,
                      const int* __restrict__ rowptr, const float* __restrict__ y,
                      const float* __restrict__ T, float* __restrict__ out, int N) {
    int n = (blockIdx.x * blockDim.x + threadIdx.x) >> 6;
    int lane = threadIdx.x & 63;
    if (n >= N) return;
    int r0 = rowptr[n], r1 = rowptr[n + 1];
    float acc = 0.0f;
    for (int j = r0; j < r1; ++j) {
        float2 lp = lerpP[j];
        int i0 = (int)lp.x;
        float f = lp.y;
        const float* tp = T + (size_t)i0 * 448 + 384 + lane;
        float w0 = tp[0], w1 = tp[448];
        float w2v = w0 + f * (w1 - w0);
        acc += y[(size_t)srcP[j] * 64 + lane] * w2v;
    }
#pragma unroll
    for (int off = 32; off > 0; off >>= 1) acc += __shfl_xor(acc, off, 64);
    if (lane == 0) out[n] = acc * (0.51298917604257706f / 8.0f);
}

extern "C" void kernel_launch(void* const* d_in, const int* in_sizes, int n_in,
                              void* d_out, int out_size, void* d_ws, size_t ws_size,
                              hipStream_t stream) {
    const float* evec = (const float*)d_in[0];
    const float* elen = (const float*)d_in[1];
    const float* W1a  = (const float*)d_in[2];
    const float* W1b  = (const float*)d_in[3];
    const float* W2a  = (const float*)d_in[4];
    const float* W2b  = (const float*)d_in[5];
    const int* esrc   = (const int*)d_in[6];
    const int* edst   = (const int*)d_in[7];
    const int E = in_sizes[1];
    const int N = out_size;
    float* out = (float*)d_out;

    char* ws = (char*)d_ws;
    size_t off = 0;
    auto alloc = [&](size_t bytes) -> void* {
        void* p = ws + off;
        off = (off + bytes + 255) & ~(size_t)255;
        return p;
    };

    int*    deg    = (int*)alloc((size_t)N * 4);
    int*    cursor = (int*)alloc((size_t)N * 4);
    int*    rowptr = (int*)alloc((size_t)(N + 1) * 4);
    float4* shP4   = (float4*)alloc((size_t)E * 64);
    int*    srcP   = (int*)alloc((size_t)E * 4);
    float2* lerpP  = (float2*)alloc((size_t)E * 8);
    float4* dotsP  = (float4*)alloc((size_t)E * 16);
    float4* x4     = (float4*)alloc((size_t)N * 64);
    float*  y      = (float*)alloc((size_t)N * 64 * 4);

    int lbins = LBINS;
    if (ws_size > off) {
        size_t avail = ws_size - off;
        size_t maxbins = avail / (448 * 4);
        if ((size_t)lbins > maxbins) lbins = (int)((maxbins / BPB) * BPB);
    }
    if (lbins < 2 * BPB) lbins = 2 * BPB;
    float* T = (float*)alloc((size_t)lbins * 448 * 4);

    hipMemsetAsync(deg, 0, (size_t)N * 4, stream);

    k_table<<<lbins / BPB, 256, 0, stream>>>(W1a, W1b, W2a, W2b, T, lbins);
    k_hist<<<(E + 255) / 256, 256, 0, stream>>>(edst, deg, E);
    k_scan<<<1, 1024, 0, stream>>>(deg, rowptr, N);
    hipMemcpyAsync(cursor, rowptr, (size_t)N * 4, hipMemcpyDeviceToDevice, stream);
    k_scatter<<<(E + 255) / 256, 256, 0, stream>>>(evec, elen, esrc, edst, cursor,
                                                   shP4, srcP, lerpP, E, lbins);
    k_x<<<(N + 255) / 256, 256, 0, stream>>>(shP4, rowptr, x4, N);
    k_dots<<<(E + 255) / 256, 256, 0, stream>>>(shP4, srcP, x4, dotsP, E);
    k_hy<<<N, 128, 0, stream>>>(dotsP, lerpP, rowptr, T, y, N);
    {
        long long threads = (long long)N * 64;
        int blocks = (int)((threads + 255) / 256);
        k_out<<<blocks, 256, 0, stream>>>(srcP, lerpP, rowptr, y, T, out, N);
    }
}

// Round 5
// 191.398 us; speedup vs baseline: 2.2039x; 1.0966x over previous
//
#include <hip/hip_runtime.h>
#include <math.h>

#define BPB 8              // bins per block in table build
static const int LBINS = 2048;   // 2048*448*4 = 3.67 MB -> fits 4 MB per-XCD L2

// ---------------- spherical harmonics l=0..3 (component norm, unit input) ----------------
__device__ __forceinline__ void sph_l3(float x, float y, float z, float* sh) {
    const float s3   = 1.7320508075688772f;
    const float s5   = 2.23606797749979f;
    const float s7   = 2.6457513110645906f;
    const float s15  = 3.872983346207417f;
    const float s105 = 10.246950765959598f;
    const float c358 = 2.0916500663351889f;  // sqrt(35/8)
    const float c218 = 1.6201851746019651f;  // sqrt(21/8)
    float x2 = x * x, y2 = y * y, z2 = z * z;
    sh[0]  = 1.0f;
    sh[1]  = s3 * x;
    sh[2]  = s3 * y;
    sh[3]  = s3 * z;
    sh[4]  = s15 * x * z;
    sh[5]  = s15 * x * y;
    sh[6]  = 0.5f * s5 * (2.0f * y2 - x2 - z2);
    sh[7]  = s15 * y * z;
    sh[8]  = 0.5f * s15 * (z2 - x2);
    sh[9]  = c358 * x * (3.0f * z2 - x2);
    sh[10] = s105 * x * y * z;
    sh[11] = c218 * x * (4.0f * y2 - z2 - x2);
    sh[12] = 0.5f * s7 * y * (2.0f * y2 - 3.0f * z2 - 3.0f * x2);
    sh[13] = c218 * z * (4.0f * y2 - z2 - x2);
    sh[14] = 0.5f * s105 * y * (z2 - x2);
    sh[15] = c358 * z * (z2 - 3.0f * x2);
}

// ---------------- K0: build weight tables T[lbins][448] = {w1[384]/16, w2[64]/16}(len) ----
// grid (lbins/BPB, 2): y=0 -> outputs [0,224); y=1 -> W2b cols (wave 0) + W1b [224,384)
template<int STR>
__device__ __forceinline__ void gemm8(const float* __restrict__ col,
                                      const float (*__restrict__ hs)[256], float* acc) {
#pragma unroll 4
    for (int cc = 0; cc < 256; ++cc) {
        float w = col[(size_t)cc * STR];
#pragma unroll
        for (int b = 0; b < BPB; ++b) acc[b] += hs[b][cc] * w;
    }
}

__global__ __launch_bounds__(256) void k_table(const float* __restrict__ W1a,
                                               const float* __restrict__ W1b,
                                               const float* __restrict__ W2a,
                                               const float* __restrict__ W2b,
                                               float* __restrict__ T, int lbins) {
    __shared__ float h1s[BPB][256];
    __shared__ float h2s[BPB][256];
    const int c = threadIdx.x;
    const int bin0 = blockIdx.x * BPB;
    const int half = blockIdx.y;
    const float inv_s3 = 0.57735026918962576f;
    const float bin2len = 4.0f / (float)(lbins - 1);
    float w1a0 = W1a[c], w1a1 = W1a[256 + c], w1a2 = W1a[512 + c];
    float w2a0 = W2a[c], w2a1 = W2a[256 + c], w2a2 = W2a[512 + c];
#pragma unroll
    for (int b = 0; b < BPB; ++b) {
        float len = (float)(bin0 + b) * bin2len;
        float d0 = len * 0.5f;
        float d1 = (len - 2.0f) * 0.5f;
        float d2 = (len - 4.0f) * 0.5f;
        float b0 = expf(-d0 * d0) * (1.0f / 1.12f);
        float b1 = expf(-d1 * d1) * (1.0f / 1.12f);
        float b2 = expf(-d2 * d2) * (1.0f / 1.12f);
        h1s[b][c] = fmaxf((b0 * w1a0 + b1 * w1a1 + b2 * w1a2) * inv_s3, 0.0f);
        if (half == 1)
            h2s[b][c] = fmaxf((b0 * w2a0 + b1 * w2a1 + b2 * w2a2) * inv_s3, 0.0f);
    }
    __syncthreads();

    float acc[BPB];
#pragma unroll
    for (int b = 0; b < BPB; ++b) acc[b] = 0.0f;
    int o = -1;  // final output column in [0,448)
    if (half == 0) {
        if (c < 224) {
            o = c;
            gemm8<384>(W1b + o, h1s, acc);
        }
    } else {
        if (c < 64) {                 // wave 0: the 64 W2b columns
            o = 384 + c;
            gemm8<64>(W2b + c, h2s, acc);
        } else if (c < 224) {         // waves 1-3: W1b [224,384)
            o = 160 + c;              // 224 + (c-64)
            gemm8<384>(W1b + o, h1s, acc);
        }
    }
    if (o >= 0) {
#pragma unroll
        for (int b = 0; b < BPB; ++b)
            T[(size_t)(bin0 + b) * 448 + o] = acc[b] * (1.0f / 16.0f);
    }
}

// ---------------- CSR build ----------------------------------------------------------------
__global__ void k_hist(const int* __restrict__ edst, int* __restrict__ deg, int E) {
    int e = blockIdx.x * blockDim.x + threadIdx.x;
    if (e < E) atomicAdd(&deg[edst[e]], 1);
}

__global__ void k_scan(const int* __restrict__ deg, int* __restrict__ rowptr, int N) {
    __shared__ int part[1024];
    int t = threadIdx.x;
    int chunk = (N + 1023) >> 10;
    int s = t * chunk;
    int epos = s + chunk; if (epos > N) epos = N;
    int sum = 0;
    for (int i = s; i < epos; ++i) sum += deg[i];
    part[t] = sum;
    __syncthreads();
    for (int off = 1; off < 1024; off <<= 1) {
        int v = (t >= off) ? part[t - off] : 0;
        __syncthreads();
        part[t] += v;
        __syncthreads();
    }
    int run = (t == 0) ? 0 : part[t - 1];
    for (int i = s; i < epos; ++i) { rowptr[i] = run; run += deg[i]; }
    if (t == 1023) rowptr[N] = part[1023];
}

// ---------------- K3: scatter edges into perm order, materializing everything ---------------
__global__ void k_scatter(const float* __restrict__ evec, const float* __restrict__ elen,
                          const int* __restrict__ esrc, const int* __restrict__ edst,
                          int* __restrict__ cursor,   // preloaded copy of rowptr
                          float4* __restrict__ shP4, int* __restrict__ srcP,
                          float2* __restrict__ lerpP, int E, int lbins) {
    int e = blockIdx.x * blockDim.x + threadIdx.x;
    if (e >= E) return;
    int d = edst[e];
    int pos = atomicAdd(&cursor[d], 1);

    float vx = evec[3 * e], vy = evec[3 * e + 1], vz = evec[3 * e + 2];
    float nrm = sqrtf(vx * vx + vy * vy + vz * vz);
    float inv = 1.0f / (nrm + 1e-12f);
    float sh[16];
    sph_l3(vx * inv, vy * inv, vz * inv, sh);
    float4* sp = shP4 + (size_t)pos * 4;
    sp[0] = make_float4(sh[0], sh[1], sh[2], sh[3]);
    sp[1] = make_float4(sh[4], sh[5], sh[6], sh[7]);
    sp[2] = make_float4(sh[8], sh[9], sh[10], sh[11]);
    sp[3] = make_float4(sh[12], sh[13], sh[14], sh[15]);
    srcP[pos] = esrc[e];

    float len = elen[e];
    float p = fminf(fmaxf(len, 0.0f), 4.0f) * ((float)(lbins - 1) / 4.0f);
    int i0 = (int)p;
    if (i0 > lbins - 2) i0 = lbins - 2;
    lerpP[pos] = make_float2((float)i0, p - (float)i0);
}

// ---------------- K4: x[n][16] = inv_nn * sum rows of shP   (thread per node, seq reads) ----
__global__ void k_x(const float4* __restrict__ shP4, const int* __restrict__ rowptr,
                    float4* __restrict__ x4, int N) {
    int n = blockIdx.x * blockDim.x + threadIdx.x;
    if (n >= N) return;
    float4 a0 = make_float4(0, 0, 0, 0), a1 = a0, a2 = a0, a3 = a0;
    int r0 = rowptr[n], r1 = rowptr[n + 1];
    for (int j = r0; j < r1; ++j) {
        const float4* sp = shP4 + (size_t)j * 4;
        float4 s0 = sp[0], s1 = sp[1], s2 = sp[2], s3 = sp[3];
        a0.x += s0.x; a0.y += s0.y; a0.z += s0.z; a0.w += s0.w;
        a1.x += s1.x; a1.y += s1.y; a1.z += s1.z; a1.w += s1.w;
        a2.x += s2.x; a2.y += s2.y; a2.z += s2.z; a2.w += s2.w;
        a3.x += s3.x; a3.y += s3.y; a3.z += s3.z; a3.w += s3.w;
    }
    const float inv_nn = 0.51298917604257706f;
    float4* xp = x4 + (size_t)n * 4;
    xp[0] = make_float4(a0.x * inv_nn, a0.y * inv_nn, a0.z * inv_nn, a0.w * inv_nn);
    xp[1] = make_float4(a1.x * inv_nn, a1.y * inv_nn, a1.z * inv_nn, a1.w * inv_nn);
    xp[2] = make_float4(a2.x * inv_nn, a2.y * inv_nn, a2.z * inv_nn, a2.w * inv_nn);
    xp[3] = make_float4(a3.x * inv_nn, a3.y * inv_nn, a3.z * inv_nn, a3.w * inv_nn);
}

// ---------------- K5: dotsP[j] (thread per perm-slot; seq shP read, 1-hop x gather) ---------
__global__ void k_dots(const float4* __restrict__ shP4, const int* __restrict__ srcP,
                       const float4* __restrict__ x4, float4* __restrict__ dotsP, int E) {
    int j = blockIdx.x * blockDim.x + threadIdx.x;
    if (j >= E) return;
    const float4* sp = shP4 + (size_t)j * 4;
    float4 s0 = sp[0], s1 = sp[1], s2 = sp[2], s3 = sp[3];
    const float4* xr = x4 + (size_t)srcP[j] * 4;
    float4 x0 = xr[0], x1 = xr[1], x2 = xr[2], x3 = xr[3];
    float d0 = x0.x * s0.x;
    float d1 = x0.y * s0.y + x0.z * s0.z + x0.w * s0.w;
    float d2 = x1.x * s1.x + x1.y * s1.y + x1.z * s1.z + x1.w * s1.w + x2.x * s2.x;
    float d3 = x2.y * s2.y + x2.z * s2.z + x2.w * s2.w
             + x3.x * s3.x + x3.y * s3.y + x3.z * s3.z + x3.w * s3.w;
    const float rs3 = 0.57735026918962576f;
    const float rs5 = 0.44721359549995793f;
    const float rs7 = 0.37796447300922720f;
    dotsP[j] = make_float4(d0, d1 * rs3, d2 * rs5, d3 * rs7);
}

// ---------------- K6: per-node h[96] -> activations -> y[n][64]  (block 128 per node) ------
__global__ __launch_bounds__(128) void k_hy(const float4* __restrict__ dotsP,
                                            const float2* __restrict__ lerpP,
                                            const int* __restrict__ rowptr,
                                            const float* __restrict__ T,
                                            float* __restrict__ y, int N) {
    int n = blockIdx.x;
    if (n >= N) return;
    int kk = threadIdx.x;
    __shared__ float hs[96];
    int r0 = rowptr[n], r1 = rowptr[n + 1];
    if (kk < 96) {
        float acc = 0.0f;
        for (int j = r0; j < r1; ++j) {
            float4 dt = dotsP[j];
            float2 lp = lerpP[j];
            int i0 = (int)lp.x;
            float f = lp.y;
            const float* tp = T + (size_t)i0 * 448 + kk;
            float a0 = tp[0],   b0 = tp[448];
            float a1 = tp[96],  b1 = tp[448 + 96];
            float a2 = tp[192], b2 = tp[448 + 192];
            float a3 = tp[288], b3 = tp[448 + 288];
            acc += dt.x * (a0 + f * (b0 - a0)) + dt.y * (a1 + f * (b1 - a1))
                 + dt.z * (a2 + f * (b2 - a2)) + dt.w * (a3 + f * (b3 - a3));
        }
        const float scale = 0.25649458802128853f;  // 0.5 * inv_nn
        hs[kk] = acc * scale;
    }
    __syncthreads();
    int t = threadIdx.x;
    if (t < 64) {
        float outv;
        if (t < 32) {
            float v = hs[t];
            outv = (t < 16) ? fmaxf(v, 0.0f) : fabsf(v);
        } else {
            int kg = t - 32;
            float g = hs[32 + kg];
            float vv = hs[64 + kg];
            float ga = (kg < 8 || (kg >= 16 && kg < 24)) ? fmaxf(g, 0.0f) : tanhf(g);
            outv = ga * vv;
        }
        y[(size_t)n * 64 + t] = outv;
    }
}

// ---------------- K7: out[n] = inv_nn/8 * sum_j y[srcP[j]]·w2(lerpP[j])  (wave/node) --------
__global__ void k_out(const int* __restrict__ srcP, const float2* __restrict__ lerpP,
                      const int* __restrict__ rowptr, const float* __restrict__ y,
                      const float* __restrict__ T, float* __restrict__ out, int N) {
    int n = (blockIdx.x * blockDim.x + threadIdx.x) >> 6;
    int lane = threadIdx.x & 63;
    if (n >= N) return;
    int r0 = rowptr[n], r1 = rowptr[n + 1];
    float acc = 0.0f;
    for (int j = r0; j < r1; ++j) {
        float2 lp = lerpP[j];
        int i0 = (int)lp.x;
        float f = lp.y;
        const float* tp = T + (size_t)i0 * 448 + 384 + lane;
        float w0 = tp[0], w1 = tp[448];
        float w2v = w0 + f * (w1 - w0);
        acc += y[(size_t)srcP[j] * 64 + lane] * w2v;
    }
#pragma unroll
    for (int off = 32; off > 0; off >>= 1) acc += __shfl_xor(acc, off, 64);
    if (lane == 0) out[n] = acc * (0.51298917604257706f / 8.0f);
}

extern "C" void kernel_launch(void* const* d_in, const int* in_sizes, int n_in,
                              void* d_out, int out_size, void* d_ws, size_t ws_size,
                              hipStream_t stream) {
    const float* evec = (const float*)d_in[0];
    const float* elen = (const float*)d_in[1];
    const float* W1a  = (const float*)d_in[2];
    const float* W1b  = (const float*)d_in[3];
    const float* W2a  = (const float*)d_in[4];
    const float* W2b  = (const float*)d_in[5];
    const int* esrc   = (const int*)d_in[6];
    const int* edst   = (const int*)d_in[7];
    const int E = in_sizes[1];
    const int N = out_size;
    float* out = (float*)d_out;

    char* ws = (char*)d_ws;
    size_t off = 0;
    auto alloc = [&](size_t bytes) -> void* {
        void* p = ws + off;
        off = (off + bytes + 255) & ~(size_t)255;
        return p;
    };

    int*    deg    = (int*)alloc((size_t)N * 4);
    int*    cursor = (int*)alloc((size_t)N * 4);
    int*    rowptr = (int*)alloc((size_t)(N + 1) * 4);
    float4* shP4   = (float4*)alloc((size_t)E * 64);
    int*    srcP   = (int*)alloc((size_t)E * 4);
    float2* lerpP  = (float2*)alloc((size_t)E * 8);
    float4* dotsP  = (float4*)alloc((size_t)E * 16);
    float4* x4     = (float4*)alloc((size_t)N * 64);
    float*  y      = (float*)alloc((size_t)N * 64 * 4);

    int lbins = LBINS;
    if (ws_size > off) {
        size_t avail = ws_size - off;
        size_t maxbins = avail / (448 * 4);
        if ((size_t)lbins > maxbins) lbins = (int)((maxbins / BPB) * BPB);
    }
    if (lbins < 2 * BPB) lbins = 2 * BPB;
    float* T = (float*)alloc((size_t)lbins * 448 * 4);

    hipMemsetAsync(deg, 0, (size_t)N * 4, stream);

    k_table<<<dim3(lbins / BPB, 2), 256, 0, stream>>>(W1a, W1b, W2a, W2b, T, lbins);
    k_hist<<<(E + 255) / 256, 256, 0, stream>>>(edst, deg, E);
    k_scan<<<1, 1024, 0, stream>>>(deg, rowptr, N);
    hipMemcpyAsync(cursor, rowptr, (size_t)N * 4, hipMemcpyDeviceToDevice, stream);
    k_scatter<<<(E + 255) / 256, 256, 0, stream>>>(evec, elen, esrc, edst, cursor,
                                                   shP4, srcP, lerpP, E, lbins);
    k_x<<<(N + 255) / 256, 256, 0, stream>>>(shP4, rowptr, x4, N);
    k_dots<<<(E + 255) / 256, 256, 0, stream>>>(shP4, srcP, x4, dotsP, E);
    k_hy<<<N, 128, 0, stream>>>(dotsP, lerpP, rowptr, T, y, N);
    {
        long long threads = (long long)N * 64;
        int blocks = (int)((threads + 255) / 256);
        k_out<<<blocks, 256, 0, stream>>>(srcP, lerpP, rowptr, y, T, out, N);
    }
}

// Round 6
// 182.745 us; speedup vs baseline: 2.3083x; 1.0474x over previous
//
#include <hip/hip_runtime.h>
#include <math.h>

#define BPB 4              // bins per block in table build
static const int LBINS = 2048;   // Tp = 2048*448*4B = 3.67 MB -> fits 4 MB per-XCD L2

__device__ __forceinline__ unsigned short f2bf(float f) {
    unsigned int u = __float_as_uint(f);
    unsigned int r = (u + 0x7FFFu + ((u >> 16) & 1u)) >> 16;   // RTN-even
    return (unsigned short)r;
}
__device__ __forceinline__ float bflo(unsigned int u) { return __uint_as_float(u << 16); }
__device__ __forceinline__ float bfhi(unsigned int u) { return __uint_as_float(u & 0xFFFF0000u); }

// ---------------- spherical harmonics l=0..3 (component norm, unit input) ----------------
__device__ __forceinline__ void sph_l3(float x, float y, float z, float* sh) {
    const float s3   = 1.7320508075688772f;
    const float s5   = 2.23606797749979f;
    const float s7   = 2.6457513110645906f;
    const float s15  = 3.872983346207417f;
    const float s105 = 10.246950765959598f;
    const float c358 = 2.0916500663351889f;  // sqrt(35/8)
    const float c218 = 1.6201851746019651f;  // sqrt(21/8)
    float x2 = x * x, y2 = y * y, z2 = z * z;
    sh[0]  = 1.0f;
    sh[1]  = s3 * x;
    sh[2]  = s3 * y;
    sh[3]  = s3 * z;
    sh[4]  = s15 * x * z;
    sh[5]  = s15 * x * y;
    sh[6]  = 0.5f * s5 * (2.0f * y2 - x2 - z2);
    sh[7]  = s15 * y * z;
    sh[8]  = 0.5f * s15 * (z2 - x2);
    sh[9]  = c358 * x * (3.0f * z2 - x2);
    sh[10] = s105 * x * y * z;
    sh[11] = c218 * x * (4.0f * y2 - z2 - x2);
    sh[12] = 0.5f * s7 * y * (2.0f * y2 - 3.0f * z2 - 3.0f * x2);
    sh[13] = c218 * z * (4.0f * y2 - z2 - x2);
    sh[14] = 0.5f * s105 * y * (z2 - x2);
    sh[15] = c358 * z * (z2 - 3.0f * x2);
}

// ---------------- K0: build packed table Tp[i][k] = bf16x2{ row_i[k], row_{i+1}[k] } -------
// value(i,k) for k<384: w1(len_i)[k]/16 ; for k>=384: w2(len_i)[k-384]/16
template<int STR>
__device__ __forceinline__ void gemmB(const float* __restrict__ col,
                                      const float (*__restrict__ hs)[256], float* acc) {
#pragma unroll 8
    for (int cc = 0; cc < 256; ++cc) {
        float w = col[(size_t)cc * STR];
#pragma unroll
        for (int b = 0; b < BPB; ++b) acc[b] += hs[b][cc] * w;
    }
}

__global__ __launch_bounds__(256) void k_table(const float* __restrict__ W1a,
                                               const float* __restrict__ W1b,
                                               const float* __restrict__ W2a,
                                               const float* __restrict__ W2b,
                                               unsigned int* __restrict__ Tp, int lbins) {
    __shared__ float h1s[BPB][256];
    __shared__ float h2s[BPB][256];
    const int c = threadIdx.x;
    const int bin0 = blockIdx.x * BPB;
    const int half = blockIdx.y;
    const float inv_s3 = 0.57735026918962576f;
    const float bin2len = 4.0f / (float)(lbins - 1);
    float w1a0 = W1a[c], w1a1 = W1a[256 + c], w1a2 = W1a[512 + c];
    float w2a0 = W2a[c], w2a1 = W2a[256 + c], w2a2 = W2a[512 + c];
#pragma unroll
    for (int b = 0; b < BPB; ++b) {
        float len = (float)(bin0 + b) * bin2len;
        float d0 = len * 0.5f;
        float d1 = (len - 2.0f) * 0.5f;
        float d2 = (len - 4.0f) * 0.5f;
        float b0 = expf(-d0 * d0) * (1.0f / 1.12f);
        float b1 = expf(-d1 * d1) * (1.0f / 1.12f);
        float b2 = expf(-d2 * d2) * (1.0f / 1.12f);
        h1s[b][c] = fmaxf((b0 * w1a0 + b1 * w1a1 + b2 * w1a2) * inv_s3, 0.0f);
        if (half == 1)
            h2s[b][c] = fmaxf((b0 * w2a0 + b1 * w2a1 + b2 * w2a2) * inv_s3, 0.0f);
    }
    __syncthreads();

    float acc[BPB];
#pragma unroll
    for (int b = 0; b < BPB; ++b) acc[b] = 0.0f;
    int o = -1;  // output column in [0,448)
    if (half == 0) {
        if (c < 224) { o = c; gemmB<384>(W1b + o, h1s, acc); }
    } else {
        if (c < 64)       { o = 384 + c; gemmB<64>(W2b + c, h2s, acc); }
        else if (c < 224) { o = 160 + c; gemmB<384>(W1b + (160 + c), h1s, acc); }
    }
    if (o >= 0) {
        unsigned short* Ts = (unsigned short*)Tp;
#pragma unroll
        for (int b = 0; b < BPB; ++b) {
            int i = bin0 + b;
            unsigned short hv = f2bf(acc[b] * (1.0f / 16.0f));
            Ts[((size_t)i * 448 + o) * 2] = hv;                        // lo slot of row i
            if (i > 0) Ts[((size_t)(i - 1) * 448 + o) * 2 + 1] = hv;   // hi slot of row i-1
        }
    }
}

// ---------------- CSR build ----------------------------------------------------------------
__global__ void k_hist(const int* __restrict__ edst, int* __restrict__ deg, int E) {
    int e = blockIdx.x * blockDim.x + threadIdx.x;
    if (e < E) atomicAdd(&deg[edst[e]], 1);
}

__global__ void k_scan(const int* __restrict__ deg, int* __restrict__ rowptr,
                       int* __restrict__ cursor, int N) {
    __shared__ int part[1024];
    int t = threadIdx.x;
    int chunk = (N + 1023) >> 10;
    int s = t * chunk;
    int epos = s + chunk; if (epos > N) epos = N;
    int sum = 0;
    for (int i = s; i < epos; ++i) sum += deg[i];
    part[t] = sum;
    __syncthreads();
    for (int off = 1; off < 1024; off <<= 1) {
        int v = (t >= off) ? part[t - off] : 0;
        __syncthreads();
        part[t] += v;
        __syncthreads();
    }
    int run = (t == 0) ? 0 : part[t - 1];
    for (int i = s; i < epos; ++i) { rowptr[i] = run; cursor[i] = run; run += deg[i]; }
    if (t == 1023) rowptr[N] = part[1023];
}

// ---------------- K3: scatter edges into perm order, materializing everything ---------------
__global__ void k_scatter(const float* __restrict__ evec, const float* __restrict__ elen,
                          const int* __restrict__ esrc, const int* __restrict__ edst,
                          int* __restrict__ cursor,   // preloaded copy of rowptr
                          float4* __restrict__ shP4, int* __restrict__ srcP,
                          float2* __restrict__ lerpP, int E, int lbins) {
    int e = blockIdx.x * blockDim.x + threadIdx.x;
    if (e >= E) return;
    int d = edst[e];
    int pos = atomicAdd(&cursor[d], 1);

    float vx = evec[3 * e], vy = evec[3 * e + 1], vz = evec[3 * e + 2];
    float nrm = sqrtf(vx * vx + vy * vy + vz * vz);
    float inv = 1.0f / (nrm + 1e-12f);
    float sh[16];
    sph_l3(vx * inv, vy * inv, vz * inv, sh);
    float4* sp = shP4 + (size_t)pos * 4;
    sp[0] = make_float4(sh[0], sh[1], sh[2], sh[3]);
    sp[1] = make_float4(sh[4], sh[5], sh[6], sh[7]);
    sp[2] = make_float4(sh[8], sh[9], sh[10], sh[11]);
    sp[3] = make_float4(sh[12], sh[13], sh[14], sh[15]);
    srcP[pos] = esrc[e];

    float len = elen[e];
    float p = fminf(fmaxf(len, 0.0f), 4.0f) * ((float)(lbins - 1) / 4.0f);
    int i0 = (int)p;
    if (i0 > lbins - 2) i0 = lbins - 2;
    lerpP[pos] = make_float2((float)i0, p - (float)i0);
}

// ---------------- K4: x[n][16] = inv_nn * sum rows of shP   (thread per node, seq reads) ----
__global__ void k_x(const float4* __restrict__ shP4, const int* __restrict__ rowptr,
                    float4* __restrict__ x4, int N) {
    int n = blockIdx.x * blockDim.x + threadIdx.x;
    if (n >= N) return;
    float4 a0 = make_float4(0, 0, 0, 0), a1 = a0, a2 = a0, a3 = a0;
    int r0 = rowptr[n], r1 = rowptr[n + 1];
    for (int j = r0; j < r1; ++j) {
        const float4* sp = shP4 + (size_t)j * 4;
        float4 s0 = sp[0], s1 = sp[1], s2 = sp[2], s3 = sp[3];
        a0.x += s0.x; a0.y += s0.y; a0.z += s0.z; a0.w += s0.w;
        a1.x += s1.x; a1.y += s1.y; a1.z += s1.z; a1.w += s1.w;
        a2.x += s2.x; a2.y += s2.y; a2.z += s2.z; a2.w += s2.w;
        a3.x += s3.x; a3.y += s3.y; a3.z += s3.z; a3.w += s3.w;
    }
    const float inv_nn = 0.51298917604257706f;
    float4* xp = x4 + (size_t)n * 4;
    xp[0] = make_float4(a0.x * inv_nn, a0.y * inv_nn, a0.z * inv_nn, a0.w * inv_nn);
    xp[1] = make_float4(a1.x * inv_nn, a1.y * inv_nn, a1.z * inv_nn, a1.w * inv_nn);
    xp[2] = make_float4(a2.x * inv_nn, a2.y * inv_nn, a2.z * inv_nn, a2.w * inv_nn);
    xp[3] = make_float4(a3.x * inv_nn, a3.y * inv_nn, a3.z * inv_nn, a3.w * inv_nn);
}

// ---------------- K5: dotsP[j] (thread per perm-slot; seq shP read, 1-hop x gather) ---------
__global__ void k_dots(const float4* __restrict__ shP4, const int* __restrict__ srcP,
                       const float4* __restrict__ x4, float4* __restrict__ dotsP, int E) {
    int j = blockIdx.x * blockDim.x + threadIdx.x;
    if (j >= E) return;
    const float4* sp = shP4 + (size_t)j * 4;
    float4 s0 = sp[0], s1 = sp[1], s2 = sp[2], s3 = sp[3];
    const float4* xr = x4 + (size_t)srcP[j] * 4;
    float4 x0 = xr[0], x1 = xr[1], x2 = xr[2], x3 = xr[3];
    float d0 = x0.x * s0.x;
    float d1 = x0.y * s0.y + x0.z * s0.z + x0.w * s0.w;
    float d2 = x1.x * s1.x + x1.y * s1.y + x1.z * s1.z + x1.w * s1.w + x2.x * s2.x;
    float d3 = x2.y * s2.y + x2.z * s2.z + x2.w * s2.w
             + x3.x * s3.x + x3.y * s3.y + x3.z * s3.z + x3.w * s3.w;
    const float rs3 = 0.57735026918962576f;
    const float rs5 = 0.44721359549995793f;
    const float rs7 = 0.37796447300922720f;
    dotsP[j] = make_float4(d0, d1 * rs3, d2 * rs5, d3 * rs7);
}

// ---------------- K6: per-node h[96] -> activations -> y[n][64]  (block 128 per node) ------
__global__ __launch_bounds__(128) void k_hy(const float4* __restrict__ dotsP,
                                            const float2* __restrict__ lerpP,
                                            const int* __restrict__ rowptr,
                                            const unsigned int* __restrict__ Tp,
                                            float* __restrict__ y, int N) {
    int n = blockIdx.x;
    if (n >= N) return;
    int kk = threadIdx.x;
    __shared__ float hs[96];
    int r0 = rowptr[n], r1 = rowptr[n + 1];
    if (kk < 96) {
        float acc = 0.0f;
        for (int j = r0; j < r1; ++j) {
            float4 dt = dotsP[j];
            float2 lp = lerpP[j];
            int i0 = (int)lp.x;
            float f = lp.y;
            const unsigned int* tp = Tp + (size_t)i0 * 448 + kk;
            unsigned int u0 = tp[0], u1 = tp[96], u2 = tp[192], u3 = tp[288];
            float a0 = bflo(u0), b0 = bfhi(u0);
            float a1 = bflo(u1), b1 = bfhi(u1);
            float a2 = bflo(u2), b2 = bfhi(u2);
            float a3 = bflo(u3), b3 = bfhi(u3);
            acc += dt.x * (a0 + f * (b0 - a0)) + dt.y * (a1 + f * (b1 - a1))
                 + dt.z * (a2 + f * (b2 - a2)) + dt.w * (a3 + f * (b3 - a3));
        }
        const float scale = 0.25649458802128853f;  // 0.5 * inv_nn
        hs[kk] = acc * scale;
    }
    __syncthreads();
    int t = threadIdx.x;
    if (t < 64) {
        float outv;
        if (t < 32) {
            float v = hs[t];
            outv = (t < 16) ? fmaxf(v, 0.0f) : fabsf(v);
        } else {
            int kg = t - 32;
            float g = hs[32 + kg];
            float vv = hs[64 + kg];
            float ga = (kg < 8 || (kg >= 16 && kg < 24)) ? fmaxf(g, 0.0f) : tanhf(g);
            outv = ga * vv;
        }
        y[(size_t)n * 64 + t] = outv;
    }
}

// ---------------- K7: out[n] = inv_nn/8 * sum_j y[srcP[j]]·w2(lerpP[j])  (wave/node) --------
__global__ void k_out(const int* __restrict__ srcP, const float2* __restrict__ lerpP,
                      const int* __restrict__ rowptr, const float* __restrict__ y,
                      const unsigned int* __restrict__ Tp, float* __restrict__ out, int N) {
    int n = (blockIdx.x * blockDim.x + threadIdx.x) >> 6;
    int lane = threadIdx.x & 63;
    if (n >= N) return;
    int r0 = rowptr[n], r1 = rowptr[n + 1];
    float acc = 0.0f;
    for (int j = r0; j < r1; ++j) {
        float2 lp = lerpP[j];
        int i0 = (int)lp.x;
        float f = lp.y;
        unsigned int u = Tp[(size_t)i0 * 448 + 384 + lane];
        float w0 = bflo(u), w1 = bfhi(u);
        float w2v = w0 + f * (w1 - w0);
        acc += y[(size_t)srcP[j] * 64 + lane] * w2v;
    }
#pragma unroll
    for (int off = 32; off > 0; off >>= 1) acc += __shfl_xor(acc, off, 64);
    if (lane == 0) out[n] = acc * (0.51298917604257706f / 8.0f);
}

extern "C" void kernel_launch(void* const* d_in, const int* in_sizes, int n_in,
                              void* d_out, int out_size, void* d_ws, size_t ws_size,
                              hipStream_t stream) {
    const float* evec = (const float*)d_in[0];
    const float* elen = (const float*)d_in[1];
    const float* W1a  = (const float*)d_in[2];
    const float* W1b  = (const float*)d_in[3];
    const float* W2a  = (const float*)d_in[4];
    const float* W2b  = (const float*)d_in[5];
    const int* esrc   = (const int*)d_in[6];
    const int* edst   = (const int*)d_in[7];
    const int E = in_sizes[1];
    const int N = out_size;
    float* out = (float*)d_out;

    char* ws = (char*)d_ws;
    size_t off = 0;
    auto alloc = [&](size_t bytes) -> void* {
        void* p = ws + off;
        off = (off + bytes + 255) & ~(size_t)255;
        return p;
    };

    int*    deg    = (int*)alloc((size_t)N * 4);
    int*    cursor = (int*)alloc((size_t)N * 4);
    int*    rowptr = (int*)alloc((size_t)(N + 1) * 4);
    float4* shP4   = (float4*)alloc((size_t)E * 64);
    int*    srcP   = (int*)alloc((size_t)E * 4);
    float2* lerpP  = (float2*)alloc((size_t)E * 8);
    float4* dotsP  = (float4*)alloc((size_t)E * 16);
    float4* x4     = (float4*)alloc((size_t)N * 64);
    float*  y      = (float*)alloc((size_t)N * 64 * 4);

    int lbins = LBINS;
    if (ws_size > off) {
        size_t avail = ws_size - off;
        size_t maxbins = avail / (448 * 4);
        if ((size_t)lbins > maxbins) lbins = (int)((maxbins / BPB) * BPB);
    }
    if (lbins < 2 * BPB) lbins = 2 * BPB;
    unsigned int* Tp = (unsigned int*)alloc((size_t)lbins * 448 * 4);

    hipMemsetAsync(deg, 0, (size_t)N * 4, stream);

    k_table<<<dim3(lbins / BPB, 2), 256, 0, stream>>>(W1a, W1b, W2a, W2b, Tp, lbins);
    k_hist<<<(E + 255) / 256, 256, 0, stream>>>(edst, deg, E);
    k_scan<<<1, 1024, 0, stream>>>(deg, rowptr, cursor, N);
    k_scatter<<<(E + 255) / 256, 256, 0, stream>>>(evec, elen, esrc, edst, cursor,
                                                   shP4, srcP, lerpP, E, lbins);
    k_x<<<(N + 255) / 256, 256, 0, stream>>>(shP4, rowptr, x4, N);
    k_dots<<<(E + 255) / 256, 256, 0, stream>>>(shP4, srcP, x4, dotsP, E);
    k_hy<<<N, 128, 0, stream>>>(dotsP, lerpP, rowptr, Tp, y, N);
    {
        long long threads = (long long)N * 64;
        int blocks = (int)((threads + 255) / 256);
        k_out<<<blocks, 256, 0, stream>>>(srcP, lerpP, rowptr, y, Tp, out, N);
    }
}

// Round 7
// 142.864 us; speedup vs baseline: 2.9526x; 1.2792x over previous
//
#include <hip/hip_runtime.h>
#include <math.h>

#define BPB 4              // bins per block in table build
static const int LBINS = 2048;   // Tp = 2048*448*4B = 3.67 MB -> fits 4 MB per-XCD L2

__device__ __forceinline__ unsigned short f2bf(float f) {
    unsigned int u = __float_as_uint(f);
    unsigned int r = (u + 0x7FFFu + ((u >> 16) & 1u)) >> 16;   // RTN-even
    return (unsigned short)r;
}
__device__ __forceinline__ float bflo(unsigned int u) { return __uint_as_float(u << 16); }
__device__ __forceinline__ float bfhi(unsigned int u) { return __uint_as_float(u & 0xFFFF0000u); }

// ---------------- spherical harmonics l=0..3 (component norm, unit input) ----------------
__device__ __forceinline__ void sph_l3(float x, float y, float z, float* sh) {
    const float s3   = 1.7320508075688772f;
    const float s5   = 2.23606797749979f;
    const float s7   = 2.6457513110645906f;
    const float s15  = 3.872983346207417f;
    const float s105 = 10.246950765959598f;
    const float c358 = 2.0916500663351889f;  // sqrt(35/8)
    const float c218 = 1.6201851746019651f;  // sqrt(21/8)
    float x2 = x * x, y2 = y * y, z2 = z * z;
    sh[0]  = 1.0f;
    sh[1]  = s3 * x;
    sh[2]  = s3 * y;
    sh[3]  = s3 * z;
    sh[4]  = s15 * x * z;
    sh[5]  = s15 * x * y;
    sh[6]  = 0.5f * s5 * (2.0f * y2 - x2 - z2);
    sh[7]  = s15 * y * z;
    sh[8]  = 0.5f * s15 * (z2 - x2);
    sh[9]  = c358 * x * (3.0f * z2 - x2);
    sh[10] = s105 * x * y * z;
    sh[11] = c218 * x * (4.0f * y2 - z2 - x2);
    sh[12] = 0.5f * s7 * y * (2.0f * y2 - 3.0f * z2 - 3.0f * x2);
    sh[13] = c218 * z * (4.0f * y2 - z2 - x2);
    sh[14] = 0.5f * s105 * y * (z2 - x2);
    sh[15] = c358 * z * (z2 - 3.0f * x2);
}

// ---------------- K0: build packed table Tp[i][k] = bf16x2{ row_i[k], row_{i+1}[k] } -------
template<int STR>
__device__ __forceinline__ void gemmB(const float* __restrict__ col,
                                      const float (*__restrict__ hs)[256], float* acc) {
#pragma unroll 8
    for (int cc = 0; cc < 256; ++cc) {
        float w = col[(size_t)cc * STR];
#pragma unroll
        for (int b = 0; b < BPB; ++b) acc[b] += hs[b][cc] * w;
    }
}

__global__ __launch_bounds__(256) void k_table(const float* __restrict__ W1a,
                                               const float* __restrict__ W1b,
                                               const float* __restrict__ W2a,
                                               const float* __restrict__ W2b,
                                               unsigned int* __restrict__ Tp, int lbins) {
    __shared__ float h1s[BPB][256];
    __shared__ float h2s[BPB][256];
    const int c = threadIdx.x;
    const int bin0 = blockIdx.x * BPB;
    const int half = blockIdx.y;
    const float inv_s3 = 0.57735026918962576f;
    const float bin2len = 4.0f / (float)(lbins - 1);
    float w1a0 = W1a[c], w1a1 = W1a[256 + c], w1a2 = W1a[512 + c];
    float w2a0 = W2a[c], w2a1 = W2a[256 + c], w2a2 = W2a[512 + c];
#pragma unroll
    for (int b = 0; b < BPB; ++b) {
        float len = (float)(bin0 + b) * bin2len;
        float d0 = len * 0.5f;
        float d1 = (len - 2.0f) * 0.5f;
        float d2 = (len - 4.0f) * 0.5f;
        float b0 = expf(-d0 * d0) * (1.0f / 1.12f);
        float b1 = expf(-d1 * d1) * (1.0f / 1.12f);
        float b2 = expf(-d2 * d2) * (1.0f / 1.12f);
        h1s[b][c] = fmaxf((b0 * w1a0 + b1 * w1a1 + b2 * w1a2) * inv_s3, 0.0f);
        if (half == 1)
            h2s[b][c] = fmaxf((b0 * w2a0 + b1 * w2a1 + b2 * w2a2) * inv_s3, 0.0f);
    }
    __syncthreads();

    float acc[BPB];
#pragma unroll
    for (int b = 0; b < BPB; ++b) acc[b] = 0.0f;
    int o = -1;  // output column in [0,448)
    if (half == 0) {
        if (c < 224) { o = c; gemmB<384>(W1b + o, h1s, acc); }
    } else {
        if (c < 64)       { o = 384 + c; gemmB<64>(W2b + c, h2s, acc); }
        else if (c < 224) { o = 160 + c; gemmB<384>(W1b + (160 + c), h1s, acc); }
    }
    if (o >= 0) {
        unsigned short* Ts = (unsigned short*)Tp;
#pragma unroll
        for (int b = 0; b < BPB; ++b) {
            int i = bin0 + b;
            unsigned short hv = f2bf(acc[b] * (1.0f / 16.0f));
            Ts[((size_t)i * 448 + o) * 2] = hv;                        // lo slot of row i
            if (i > 0) Ts[((size_t)(i - 1) * 448 + o) * 2 + 1] = hv;   // hi slot of row i-1
        }
    }
}

// ---------------- CSR build: hist -> 3-phase scan ------------------------------------------
__global__ void k_hist(const int* __restrict__ edst, int* __restrict__ deg, int E) {
    int e = blockIdx.x * blockDim.x + threadIdx.x;
    if (e < E) atomicAdd(&deg[edst[e]], 1);
}

// A: block sums (coalesced)
__global__ __launch_bounds__(256) void k_scanA(const int* __restrict__ deg,
                                               int* __restrict__ bsum, int N) {
    int i = blockIdx.x * 256 + threadIdx.x;
    int v = (i < N) ? deg[i] : 0;
#pragma unroll
    for (int off = 32; off > 0; off >>= 1) v += __shfl_xor(v, off, 64);
    __shared__ int s[4];
    int wid = threadIdx.x >> 6;
    if ((threadIdx.x & 63) == 0) s[wid] = v;
    __syncthreads();
    if (threadIdx.x == 0) bsum[blockIdx.x] = s[0] + s[1] + s[2] + s[3];
}

// B: scan block sums (nb <= 256), also write rowptr[N] = total
__global__ __launch_bounds__(256) void k_scanB(const int* __restrict__ bsum,
                                               int* __restrict__ bsumEx, int nb,
                                               int* __restrict__ rowptrN) {
    __shared__ int part[256];
    int t = threadIdx.x;
    part[t] = (t < nb) ? bsum[t] : 0;
    __syncthreads();
#pragma unroll
    for (int off = 1; off < 256; off <<= 1) {
        int v = (t >= off) ? part[t - off] : 0;
        __syncthreads();
        part[t] += v;
        __syncthreads();
    }
    if (t < nb) bsumEx[t] = (t == 0) ? 0 : part[t - 1];
    if (t == 255) *rowptrN = part[255];
}

// C: per-block scan + offset -> rowptr & cursor (coalesced)
__global__ __launch_bounds__(256) void k_scanC(const int* __restrict__ deg,
                                               const int* __restrict__ bsumEx,
                                               int* __restrict__ rowptr,
                                               int* __restrict__ cursor, int N) {
    __shared__ int part[256];
    int t = threadIdx.x;
    int i = blockIdx.x * 256 + t;
    part[t] = (i < N) ? deg[i] : 0;
    __syncthreads();
#pragma unroll
    for (int off = 1; off < 256; off <<= 1) {
        int v = (t >= off) ? part[t - off] : 0;
        __syncthreads();
        part[t] += v;
        __syncthreads();
    }
    if (i < N) {
        int val = bsumEx[blockIdx.x] + ((t == 0) ? 0 : part[t - 1]);
        rowptr[i] = val;
        cursor[i] = val;
    }
}

// ---------------- K3: scatter edges into perm order, materializing everything ---------------
__global__ void k_scatter(const float* __restrict__ evec, const float* __restrict__ elen,
                          const int* __restrict__ esrc, const int* __restrict__ edst,
                          int* __restrict__ cursor,   // preloaded copy of rowptr
                          float4* __restrict__ shP4, int* __restrict__ srcP,
                          float* __restrict__ lerpP, int E, int lbins) {
    int e = blockIdx.x * blockDim.x + threadIdx.x;
    if (e >= E) return;
    int d = edst[e];
    int pos = atomicAdd(&cursor[d], 1);

    float vx = evec[3 * e], vy = evec[3 * e + 1], vz = evec[3 * e + 2];
    float nrm = sqrtf(vx * vx + vy * vy + vz * vz);
    float inv = 1.0f / (nrm + 1e-12f);
    float sh[16];
    sph_l3(vx * inv, vy * inv, vz * inv, sh);
    float4* sp = shP4 + (size_t)pos * 4;
    sp[0] = make_float4(sh[0], sh[1], sh[2], sh[3]);
    sp[1] = make_float4(sh[4], sh[5], sh[6], sh[7]);
    sp[2] = make_float4(sh[8], sh[9], sh[10], sh[11]);
    sp[3] = make_float4(sh[12], sh[13], sh[14], sh[15]);
    srcP[pos] = esrc[e];

    float len = elen[e];
    float p = fminf(fmaxf(len, 0.0f), 4.0f) * ((float)(lbins - 1) / 4.0f);
    if (p > (float)(lbins - 1) - 1.0f) p = (float)(lbins - 1) - 1.0f;
    lerpP[pos] = p;   // i0 = floor(p), f = p - i0
}

// ---------------- K4: x[n][16] = inv_nn * sum rows of shP   (thread per node, seq reads) ----
__global__ void k_x(const float4* __restrict__ shP4, const int* __restrict__ rowptr,
                    float4* __restrict__ x4, int N) {
    int n = blockIdx.x * blockDim.x + threadIdx.x;
    if (n >= N) return;
    float4 a0 = make_float4(0, 0, 0, 0), a1 = a0, a2 = a0, a3 = a0;
    int r0 = rowptr[n], r1 = rowptr[n + 1];
    for (int j = r0; j < r1; ++j) {
        const float4* sp = shP4 + (size_t)j * 4;
        float4 s0 = sp[0], s1 = sp[1], s2 = sp[2], s3 = sp[3];
        a0.x += s0.x; a0.y += s0.y; a0.z += s0.z; a0.w += s0.w;
        a1.x += s1.x; a1.y += s1.y; a1.z += s1.z; a1.w += s1.w;
        a2.x += s2.x; a2.y += s2.y; a2.z += s2.z; a2.w += s2.w;
        a3.x += s3.x; a3.y += s3.y; a3.z += s3.z; a3.w += s3.w;
    }
    const float inv_nn = 0.51298917604257706f;
    float4* xp = x4 + (size_t)n * 4;
    xp[0] = make_float4(a0.x * inv_nn, a0.y * inv_nn, a0.z * inv_nn, a0.w * inv_nn);
    xp[1] = make_float4(a1.x * inv_nn, a1.y * inv_nn, a1.z * inv_nn, a1.w * inv_nn);
    xp[2] = make_float4(a2.x * inv_nn, a2.y * inv_nn, a2.z * inv_nn, a2.w * inv_nn);
    xp[3] = make_float4(a3.x * inv_nn, a3.y * inv_nn, a3.z * inv_nn, a3.w * inv_nn);
}

// ---------------- K5: dotsP[j] (thread per perm-slot; seq shP read, 1-hop x gather) ---------
__global__ void k_dots(const float4* __restrict__ shP4, const int* __restrict__ srcP,
                       const float4* __restrict__ x4, float4* __restrict__ dotsP, int E) {
    int j = blockIdx.x * blockDim.x + threadIdx.x;
    if (j >= E) return;
    const float4* sp = shP4 + (size_t)j * 4;
    float4 s0 = sp[0], s1 = sp[1], s2 = sp[2], s3 = sp[3];
    const float4* xr = x4 + (size_t)srcP[j] * 4;
    float4 x0 = xr[0], x1 = xr[1], x2 = xr[2], x3 = xr[3];
    float d0 = x0.x * s0.x;
    float d1 = x0.y * s0.y + x0.z * s0.z + x0.w * s0.w;
    float d2 = x1.x * s1.x + x1.y * s1.y + x1.z * s1.z + x1.w * s1.w + x2.x * s2.x;
    float d3 = x2.y * s2.y + x2.z * s2.z + x2.w * s2.w
             + x3.x * s3.x + x3.y * s3.y + x3.z * s3.z + x3.w * s3.w;
    const float rs3 = 0.57735026918962576f;
    const float rs5 = 0.44721359549995793f;
    const float rs7 = 0.37796447300922720f;
    dotsP[j] = make_float4(d0, d1 * rs3, d2 * rs5, d3 * rs7);
}

// ---------------- K6: per-node h[96] -> activations -> y[n][64]  (block 128 per node) ------
__global__ __launch_bounds__(128) void k_hy(const float4* __restrict__ dotsP,
                                            const float* __restrict__ lerpP,
                                            const int* __restrict__ rowptr,
                                            const unsigned int* __restrict__ Tp,
                                            float* __restrict__ y, int N) {
    int n = blockIdx.x;
    if (n >= N) return;
    int kk = threadIdx.x;
    __shared__ float hs[96];
    int r0 = rowptr[n], r1 = rowptr[n + 1];
    if (kk < 96) {
        float acc = 0.0f;
        for (int j = r0; j < r1; ++j) {
            float4 dt = dotsP[j];
            float p = lerpP[j];
            int i0 = (int)p;
            float f = p - (float)i0;
            const unsigned int* tp = Tp + (size_t)i0 * 448 + kk;
            unsigned int u0 = tp[0], u1 = tp[96], u2 = tp[192], u3 = tp[288];
            float a0 = bflo(u0), b0 = bfhi(u0);
            float a1 = bflo(u1), b1 = bfhi(u1);
            float a2 = bflo(u2), b2 = bfhi(u2);
            float a3 = bflo(u3), b3 = bfhi(u3);
            acc += dt.x * (a0 + f * (b0 - a0)) + dt.y * (a1 + f * (b1 - a1))
                 + dt.z * (a2 + f * (b2 - a2)) + dt.w * (a3 + f * (b3 - a3));
        }
        const float scale = 0.25649458802128853f;  // 0.5 * inv_nn
        hs[kk] = acc * scale;
    }
    __syncthreads();
    int t = threadIdx.x;
    if (t < 64) {
        float outv;
        if (t < 32) {
            float v = hs[t];
            outv = (t < 16) ? fmaxf(v, 0.0f) : fabsf(v);
        } else {
            int kg = t - 32;
            float g = hs[32 + kg];
            float vv = hs[64 + kg];
            float ga = (kg < 8 || (kg >= 16 && kg < 24)) ? fmaxf(g, 0.0f) : tanhf(g);
            outv = ga * vv;
        }
        y[(size_t)n * 64 + t] = outv;
    }
}

// ---------------- K7: out[n] = inv_nn/8 * sum_j y[srcP[j]]·w2(lerpP[j])  (wave/node) --------
__global__ void k_out(const int* __restrict__ srcP, const float* __restrict__ lerpP,
                      const int* __restrict__ rowptr, const float* __restrict__ y,
                      const unsigned int* __restrict__ Tp, float* __restrict__ out, int N) {
    int n = (blockIdx.x * blockDim.x + threadIdx.x) >> 6;
    int lane = threadIdx.x & 63;
    if (n >= N) return;
    int r0 = rowptr[n], r1 = rowptr[n + 1];
    float acc = 0.0f;
    for (int j = r0; j < r1; ++j) {
        float p = lerpP[j];
        int i0 = (int)p;
        float f = p - (float)i0;
        unsigned int u = Tp[(size_t)i0 * 448 + 384 + lane];
        float w0 = bflo(u), w1 = bfhi(u);
        float w2v = w0 + f * (w1 - w0);
        acc += y[(size_t)srcP[j] * 64 + lane] * w2v;
    }
#pragma unroll
    for (int off = 32; off > 0; off >>= 1) acc += __shfl_xor(acc, off, 64);
    if (lane == 0) out[n] = acc * (0.51298917604257706f / 8.0f);
}

extern "C" void kernel_launch(void* const* d_in, const int* in_sizes, int n_in,
                              void* d_out, int out_size, void* d_ws, size_t ws_size,
                              hipStream_t stream) {
    const float* evec = (const float*)d_in[0];
    const float* elen = (const float*)d_in[1];
    const float* W1a  = (const float*)d_in[2];
    const float* W1b  = (const float*)d_in[3];
    const float* W2a  = (const float*)d_in[4];
    const float* W2b  = (const float*)d_in[5];
    const int* esrc   = (const int*)d_in[6];
    const int* edst   = (const int*)d_in[7];
    const int E = in_sizes[1];
    const int N = out_size;
    float* out = (float*)d_out;

    char* ws = (char*)d_ws;
    size_t off = 0;
    auto alloc = [&](size_t bytes) -> void* {
        void* p = ws + off;
        off = (off + bytes + 255) & ~(size_t)255;
        return p;
    };

    const int nb = (N + 255) / 256;
    int*    deg    = (int*)alloc((size_t)N * 4);
    int*    cursor = (int*)alloc((size_t)N * 4);
    int*    rowptr = (int*)alloc((size_t)(N + 1) * 4);
    int*    bsum   = (int*)alloc((size_t)nb * 4);
    int*    bsumEx = (int*)alloc((size_t)nb * 4);
    float4* shP4   = (float4*)alloc((size_t)E * 64);
    int*    srcP   = (int*)alloc((size_t)E * 4);
    float*  lerpP  = (float*)alloc((size_t)E * 4);
    float4* dotsP  = (float4*)alloc((size_t)E * 16);
    float4* x4     = (float4*)alloc((size_t)N * 64);
    float*  y      = (float*)alloc((size_t)N * 64 * 4);

    int lbins = LBINS;
    if (ws_size > off) {
        size_t avail = ws_size - off;
        size_t maxbins = avail / (448 * 4);
        if ((size_t)lbins > maxbins) lbins = (int)((maxbins / BPB) * BPB);
    }
    if (lbins < 2 * BPB) lbins = 2 * BPB;
    unsigned int* Tp = (unsigned int*)alloc((size_t)lbins * 448 * 4);

    hipMemsetAsync(deg, 0, (size_t)N * 4, stream);

    k_table<<<dim3(lbins / BPB, 2), 256, 0, stream>>>(W1a, W1b, W2a, W2b, Tp, lbins);
    k_hist<<<(E + 255) / 256, 256, 0, stream>>>(edst, deg, E);
    k_scanA<<<nb, 256, 0, stream>>>(deg, bsum, N);
    k_scanB<<<1, 256, 0, stream>>>(bsum, bsumEx, nb, rowptr + N);
    k_scanC<<<nb, 256, 0, stream>>>(deg, bsumEx, rowptr, cursor, N);
    k_scatter<<<(E + 255) / 256, 256, 0, stream>>>(evec, elen, esrc, edst, cursor,
                                                   shP4, srcP, lerpP, E, lbins);
    k_x<<<(N + 255) / 256, 256, 0, stream>>>(shP4, rowptr, x4, N);
    k_dots<<<(E + 255) / 256, 256, 0, stream>>>(shP4, srcP, x4, dotsP, E);
    k_hy<<<N, 128, 0, stream>>>(dotsP, lerpP, rowptr, Tp, y, N);
    {
        long long threads = (long long)N * 64;
        int blocks = (int)((threads + 255) / 256);
        k_out<<<blocks, 256, 0, stream>>>(srcP, lerpP, rowptr, y, Tp, out, N);
    }
}

// Round 8
// 137.858 us; speedup vs baseline: 3.0599x; 1.0363x over previous
//
#include <hip/hip_runtime.h>
#include <math.h>

#define BPB 4              // bins per block in table build
static const int LBINS = 2048;   // Tp = 2048*448*4B = 3.67 MB -> fits 4 MB per-XCD L2

__device__ __forceinline__ unsigned short f2bf(float f) {
    unsigned int u = __float_as_uint(f);
    unsigned int r = (u + 0x7FFFu + ((u >> 16) & 1u)) >> 16;   // RTN-even
    return (unsigned short)r;
}
__device__ __forceinline__ float bflo(unsigned int u) { return __uint_as_float(u << 16); }
__device__ __forceinline__ float bfhi(unsigned int u) { return __uint_as_float(u & 0xFFFF0000u); }

// ---------------- spherical harmonics l=0..3 (component norm, unit input) ----------------
__device__ __forceinline__ void sph_l3(float x, float y, float z, float* sh) {
    const float s3   = 1.7320508075688772f;
    const float s5   = 2.23606797749979f;
    const float s7   = 2.6457513110645906f;
    const float s15  = 3.872983346207417f;
    const float s105 = 10.246950765959598f;
    const float c358 = 2.0916500663351889f;  // sqrt(35/8)
    const float c218 = 1.6201851746019651f;  // sqrt(21/8)
    float x2 = x * x, y2 = y * y, z2 = z * z;
    sh[0]  = 1.0f;
    sh[1]  = s3 * x;
    sh[2]  = s3 * y;
    sh[3]  = s3 * z;
    sh[4]  = s15 * x * z;
    sh[5]  = s15 * x * y;
    sh[6]  = 0.5f * s5 * (2.0f * y2 - x2 - z2);
    sh[7]  = s15 * y * z;
    sh[8]  = 0.5f * s15 * (z2 - x2);
    sh[9]  = c358 * x * (3.0f * z2 - x2);
    sh[10] = s105 * x * y * z;
    sh[11] = c218 * x * (4.0f * y2 - z2 - x2);
    sh[12] = 0.5f * s7 * y * (2.0f * y2 - 3.0f * z2 - 3.0f * x2);
    sh[13] = c218 * z * (4.0f * y2 - z2 - x2);
    sh[14] = 0.5f * s105 * y * (z2 - x2);
    sh[15] = c358 * z * (z2 - 3.0f * x2);
}

// ---------------- K0: build packed table Tp[i][k] = bf16x2{ row_i[k], row_{i+1}[k] } -------
// Also zeroes deg[] (half==0 blocks) so no separate memset dispatch is needed.
template<int STR>
__device__ __forceinline__ void gemmB(const float* __restrict__ col,
                                      const float (*__restrict__ hs)[256], float* acc) {
#pragma unroll 8
    for (int cc = 0; cc < 256; ++cc) {
        float w = col[(size_t)cc * STR];
#pragma unroll
        for (int b = 0; b < BPB; ++b) acc[b] += hs[b][cc] * w;
    }
}

__global__ __launch_bounds__(256) void k_table(const float* __restrict__ W1a,
                                               const float* __restrict__ W1b,
                                               const float* __restrict__ W2a,
                                               const float* __restrict__ W2b,
                                               unsigned int* __restrict__ Tp, int lbins,
                                               int* __restrict__ deg, int N) {
    __shared__ float h1s[BPB][256];
    __shared__ float h2s[BPB][256];
    const int c = threadIdx.x;
    const int bin0 = blockIdx.x * BPB;
    const int half = blockIdx.y;

    // fold in deg zeroing (stream order guarantees completion before k_hist)
    if (half == 0) {
        int zi = blockIdx.x * 256 + c;
        if (zi < N) deg[zi] = 0;
    }

    const float inv_s3 = 0.57735026918962576f;
    const float bin2len = 4.0f / (float)(lbins - 1);
    float w1a0 = W1a[c], w1a1 = W1a[256 + c], w1a2 = W1a[512 + c];
    float w2a0 = W2a[c], w2a1 = W2a[256 + c], w2a2 = W2a[512 + c];
#pragma unroll
    for (int b = 0; b < BPB; ++b) {
        float len = (float)(bin0 + b) * bin2len;
        float d0 = len * 0.5f;
        float d1 = (len - 2.0f) * 0.5f;
        float d2 = (len - 4.0f) * 0.5f;
        float b0 = expf(-d0 * d0) * (1.0f / 1.12f);
        float b1 = expf(-d1 * d1) * (1.0f / 1.12f);
        float b2 = expf(-d2 * d2) * (1.0f / 1.12f);
        h1s[b][c] = fmaxf((b0 * w1a0 + b1 * w1a1 + b2 * w1a2) * inv_s3, 0.0f);
        if (half == 1)
            h2s[b][c] = fmaxf((b0 * w2a0 + b1 * w2a1 + b2 * w2a2) * inv_s3, 0.0f);
    }
    __syncthreads();

    float acc[BPB];
#pragma unroll
    for (int b = 0; b < BPB; ++b) acc[b] = 0.0f;
    int o = -1;  // output column in [0,448)
    if (half == 0) {
        if (c < 224) { o = c; gemmB<384>(W1b + o, h1s, acc); }
    } else {
        if (c < 64)       { o = 384 + c; gemmB<64>(W2b + c, h2s, acc); }
        else if (c < 224) { o = 160 + c; gemmB<384>(W1b + (160 + c), h1s, acc); }
    }
    if (o >= 0) {
        unsigned short* Ts = (unsigned short*)Tp;
#pragma unroll
        for (int b = 0; b < BPB; ++b) {
            int i = bin0 + b;
            unsigned short hv = f2bf(acc[b] * (1.0f / 16.0f));
            Ts[((size_t)i * 448 + o) * 2] = hv;                        // lo slot of row i
            if (i > 0) Ts[((size_t)(i - 1) * 448 + o) * 2 + 1] = hv;   // hi slot of row i-1
        }
    }
}

// ---------------- CSR build: hist -> 3-phase scan ------------------------------------------
__global__ void k_hist(const int* __restrict__ edst, int* __restrict__ deg, int E) {
    int e = blockIdx.x * blockDim.x + threadIdx.x;
    if (e < E) atomicAdd(&deg[edst[e]], 1);
}

// A: block sums (coalesced)
__global__ __launch_bounds__(256) void k_scanA(const int* __restrict__ deg,
                                               int* __restrict__ bsum, int N) {
    int i = blockIdx.x * 256 + threadIdx.x;
    int v = (i < N) ? deg[i] : 0;
#pragma unroll
    for (int off = 32; off > 0; off >>= 1) v += __shfl_xor(v, off, 64);
    __shared__ int s[4];
    int wid = threadIdx.x >> 6;
    if ((threadIdx.x & 63) == 0) s[wid] = v;
    __syncthreads();
    if (threadIdx.x == 0) bsum[blockIdx.x] = s[0] + s[1] + s[2] + s[3];
}

// B: scan block sums (nb <= 256), also write rowptr[N] = total
__global__ __launch_bounds__(256) void k_scanB(const int* __restrict__ bsum,
                                               int* __restrict__ bsumEx, int nb,
                                               int* __restrict__ rowptrN) {
    __shared__ int part[256];
    int t = threadIdx.x;
    part[t] = (t < nb) ? bsum[t] : 0;
    __syncthreads();
#pragma unroll
    for (int off = 1; off < 256; off <<= 1) {
        int v = (t >= off) ? part[t - off] : 0;
        __syncthreads();
        part[t] += v;
        __syncthreads();
    }
    if (t < nb) bsumEx[t] = (t == 0) ? 0 : part[t - 1];
    if (t == 255) *rowptrN = part[255];
}

// C: per-block scan + offset -> rowptr & cursor (coalesced)
__global__ __launch_bounds__(256) void k_scanC(const int* __restrict__ deg,
                                               const int* __restrict__ bsumEx,
                                               int* __restrict__ rowptr,
                                               int* __restrict__ cursor, int N) {
    __shared__ int part[256];
    int t = threadIdx.x;
    int i = blockIdx.x * 256 + t;
    part[t] = (i < N) ? deg[i] : 0;
    __syncthreads();
#pragma unroll
    for (int off = 1; off < 256; off <<= 1) {
        int v = (t >= off) ? part[t - off] : 0;
        __syncthreads();
        part[t] += v;
        __syncthreads();
    }
    if (i < N) {
        int val = bsumEx[blockIdx.x] + ((t == 0) ? 0 : part[t - 1]);
        rowptr[i] = val;
        cursor[i] = val;
    }
}

// ---------------- K3: scatter edges into perm order, materializing everything ---------------
__global__ void k_scatter(const float* __restrict__ evec, const float* __restrict__ elen,
                          const int* __restrict__ esrc, const int* __restrict__ edst,
                          int* __restrict__ cursor,   // preloaded copy of rowptr
                          float4* __restrict__ shP4, int* __restrict__ srcP,
                          float* __restrict__ lerpP, int E, int lbins) {
    int e = blockIdx.x * blockDim.x + threadIdx.x;
    if (e >= E) return;
    int d = edst[e];
    int pos = atomicAdd(&cursor[d], 1);

    float vx = evec[3 * e], vy = evec[3 * e + 1], vz = evec[3 * e + 2];
    float nrm = sqrtf(vx * vx + vy * vy + vz * vz);
    float inv = 1.0f / (nrm + 1e-12f);
    float sh[16];
    sph_l3(vx * inv, vy * inv, vz * inv, sh);
    float4* sp = shP4 + (size_t)pos * 4;
    sp[0] = make_float4(sh[0], sh[1], sh[2], sh[3]);
    sp[1] = make_float4(sh[4], sh[5], sh[6], sh[7]);
    sp[2] = make_float4(sh[8], sh[9], sh[10], sh[11]);
    sp[3] = make_float4(sh[12], sh[13], sh[14], sh[15]);
    srcP[pos] = esrc[e];

    float len = elen[e];
    float p = fminf(fmaxf(len, 0.0f), 4.0f) * ((float)(lbins - 1) / 4.0f);
    if (p > (float)(lbins - 1) - 1.0f) p = (float)(lbins - 1) - 1.0f;
    lerpP[pos] = p;   // i0 = floor(p), f = p - i0
}

// ---------------- K4: x[n][16] = inv_nn * sum rows of shP   (thread per node, seq reads) ----
__global__ void k_x(const float4* __restrict__ shP4, const int* __restrict__ rowptr,
                    float4* __restrict__ x4, int N) {
    int n = blockIdx.x * blockDim.x + threadIdx.x;
    if (n >= N) return;
    float4 a0 = make_float4(0, 0, 0, 0), a1 = a0, a2 = a0, a3 = a0;
    int r0 = rowptr[n], r1 = rowptr[n + 1];
    for (int j = r0; j < r1; ++j) {
        const float4* sp = shP4 + (size_t)j * 4;
        float4 s0 = sp[0], s1 = sp[1], s2 = sp[2], s3 = sp[3];
        a0.x += s0.x; a0.y += s0.y; a0.z += s0.z; a0.w += s0.w;
        a1.x += s1.x; a1.y += s1.y; a1.z += s1.z; a1.w += s1.w;
        a2.x += s2.x; a2.y += s2.y; a2.z += s2.z; a2.w += s2.w;
        a3.x += s3.x; a3.y += s3.y; a3.z += s3.z; a3.w += s3.w;
    }
    const float inv_nn = 0.51298917604257706f;
    float4* xp = x4 + (size_t)n * 4;
    xp[0] = make_float4(a0.x * inv_nn, a0.y * inv_nn, a0.z * inv_nn, a0.w * inv_nn);
    xp[1] = make_float4(a1.x * inv_nn, a1.y * inv_nn, a1.z * inv_nn, a1.w * inv_nn);
    xp[2] = make_float4(a2.x * inv_nn, a2.y * inv_nn, a2.z * inv_nn, a2.w * inv_nn);
    xp[3] = make_float4(a3.x * inv_nn, a3.y * inv_nn, a3.z * inv_nn, a3.w * inv_nn);
}

// ---------------- K5: dotsP[j] (thread per perm-slot; seq shP read, 1-hop x gather) ---------
__global__ void k_dots(const float4* __restrict__ shP4, const int* __restrict__ srcP,
                       const float4* __restrict__ x4, float4* __restrict__ dotsP, int E) {
    int j = blockIdx.x * blockDim.x + threadIdx.x;
    if (j >= E) return;
    const float4* sp = shP4 + (size_t)j * 4;
    float4 s0 = sp[0], s1 = sp[1], s2 = sp[2], s3 = sp[3];
    const float4* xr = x4 + (size_t)srcP[j] * 4;
    float4 x0 = xr[0], x1 = xr[1], x2 = xr[2], x3 = xr[3];
    float d0 = x0.x * s0.x;
    float d1 = x0.y * s0.y + x0.z * s0.z + x0.w * s0.w;
    float d2 = x1.x * s1.x + x1.y * s1.y + x1.z * s1.z + x1.w * s1.w + x2.x * s2.x;
    float d3 = x2.y * s2.y + x2.z * s2.z + x2.w * s2.w
             + x3.x * s3.x + x3.y * s3.y + x3.z * s3.z + x3.w * s3.w;
    const float rs3 = 0.57735026918962576f;
    const float rs5 = 0.44721359549995793f;
    const float rs7 = 0.37796447300922720f;
    dotsP[j] = make_float4(d0, d1 * rs3, d2 * rs5, d3 * rs7);
}

// ---------------- K6: per-node h[96] -> activations -> y[n][64]  (block 128 per node) ------
__global__ __launch_bounds__(128) void k_hy(const float4* __restrict__ dotsP,
                                            const float* __restrict__ lerpP,
                                            const int* __restrict__ rowptr,
                                            const unsigned int* __restrict__ Tp,
                                            float* __restrict__ y, int N) {
    int n = blockIdx.x;
    if (n >= N) return;
    int kk = threadIdx.x;
    __shared__ float hs[96];
    int r0 = rowptr[n], r1 = rowptr[n + 1];
    if (kk < 96) {
        float acc = 0.0f;
        for (int j = r0; j < r1; ++j) {
            float4 dt = dotsP[j];
            float p = lerpP[j];
            int i0 = (int)p;
            float f = p - (float)i0;
            const unsigned int* tp = Tp + (size_t)i0 * 448 + kk;
            unsigned int u0 = tp[0], u1 = tp[96], u2 = tp[192], u3 = tp[288];
            float a0 = bflo(u0), b0 = bfhi(u0);
            float a1 = bflo(u1), b1 = bfhi(u1);
            float a2 = bflo(u2), b2 = bfhi(u2);
            float a3 = bflo(u3), b3 = bfhi(u3);
            acc += dt.x * (a0 + f * (b0 - a0)) + dt.y * (a1 + f * (b1 - a1))
                 + dt.z * (a2 + f * (b2 - a2)) + dt.w * (a3 + f * (b3 - a3));
        }
        const float scale = 0.25649458802128853f;  // 0.5 * inv_nn
        hs[kk] = acc * scale;
    }
    __syncthreads();
    int t = threadIdx.x;
    if (t < 64) {
        float outv;
        if (t < 32) {
            float v = hs[t];
            outv = (t < 16) ? fmaxf(v, 0.0f) : fabsf(v);
        } else {
            int kg = t - 32;
            float g = hs[32 + kg];
            float vv = hs[64 + kg];
            float ga = (kg < 8 || (kg >= 16 && kg < 24)) ? fmaxf(g, 0.0f) : tanhf(g);
            outv = ga * vv;
        }
        y[(size_t)n * 64 + t] = outv;
    }
}

// ---------------- K7: out[n] = inv_nn/8 * sum_j y[srcP[j]]·w2(lerpP[j])  (wave/node) --------
__global__ void k_out(const int* __restrict__ srcP, const float* __restrict__ lerpP,
                      const int* __restrict__ rowptr, const float* __restrict__ y,
                      const unsigned int* __restrict__ Tp, float* __restrict__ out, int N) {
    int n = (blockIdx.x * blockDim.x + threadIdx.x) >> 6;
    int lane = threadIdx.x & 63;
    if (n >= N) return;
    int r0 = rowptr[n], r1 = rowptr[n + 1];
    float acc = 0.0f;
    for (int j = r0; j < r1; ++j) {
        float p = lerpP[j];
        int i0 = (int)p;
        float f = p - (float)i0;
        unsigned int u = Tp[(size_t)i0 * 448 + 384 + lane];
        float w0 = bflo(u), w1 = bfhi(u);
        float w2v = w0 + f * (w1 - w0);
        acc += y[(size_t)srcP[j] * 64 + lane] * w2v;
    }
#pragma unroll
    for (int off = 32; off > 0; off >>= 1) acc += __shfl_xor(acc, off, 64);
    if (lane == 0) out[n] = acc * (0.51298917604257706f / 8.0f);
}

extern "C" void kernel_launch(void* const* d_in, const int* in_sizes, int n_in,
                              void* d_out, int out_size, void* d_ws, size_t ws_size,
                              hipStream_t stream) {
    const float* evec = (const float*)d_in[0];
    const float* elen = (const float*)d_in[1];
    const float* W1a  = (const float*)d_in[2];
    const float* W1b  = (const float*)d_in[3];
    const float* W2a  = (const float*)d_in[4];
    const float* W2b  = (const float*)d_in[5];
    const int* esrc   = (const int*)d_in[6];
    const int* edst   = (const int*)d_in[7];
    const int E = in_sizes[1];
    const int N = out_size;
    float* out = (float*)d_out;

    char* ws = (char*)d_ws;
    size_t off = 0;
    auto alloc = [&](size_t bytes) -> void* {
        void* p = ws + off;
        off = (off + bytes + 255) & ~(size_t)255;
        return p;
    };

    const int nb = (N + 255) / 256;
    int*    deg    = (int*)alloc((size_t)N * 4);
    int*    cursor = (int*)alloc((size_t)N * 4);
    int*    rowptr = (int*)alloc((size_t)(N + 1) * 4);
    int*    bsum   = (int*)alloc((size_t)nb * 4);
    int*    bsumEx = (int*)alloc((size_t)nb * 4);
    float4* shP4   = (float4*)alloc((size_t)E * 64);
    int*    srcP   = (int*)alloc((size_t)E * 4);
    float*  lerpP  = (float*)alloc((size_t)E * 4);
    float4* dotsP  = (float4*)alloc((size_t)E * 16);
    float4* x4     = (float4*)alloc((size_t)N * 64);
    float*  y      = (float*)alloc((size_t)N * 64 * 4);

    int lbins = LBINS;
    if (ws_size > off) {
        size_t avail = ws_size - off;
        size_t maxbins = avail / (448 * 4);
        if ((size_t)lbins > maxbins) lbins = (int)((maxbins / BPB) * BPB);
    }
    if (lbins < 2 * BPB) lbins = 2 * BPB;
    unsigned int* Tp = (unsigned int*)alloc((size_t)lbins * 448 * 4);

    k_table<<<dim3(lbins / BPB, 2), 256, 0, stream>>>(W1a, W1b, W2a, W2b, Tp, lbins, deg, N);
    k_hist<<<(E + 255) / 256, 256, 0, stream>>>(edst, deg, E);
    k_scanA<<<nb, 256, 0, stream>>>(deg, bsum, N);
    k_scanB<<<1, 256, 0, stream>>>(bsum, bsumEx, nb, rowptr + N);
    k_scanC<<<nb, 256, 0, stream>>>(deg, bsumEx, rowptr, cursor, N);
    k_scatter<<<(E + 255) / 256, 256, 0, stream>>>(evec, elen, esrc, edst, cursor,
                                                   shP4, srcP, lerpP, E, lbins);
    k_x<<<(N + 255) / 256, 256, 0, stream>>>(shP4, rowptr, x4, N);
    k_dots<<<(E + 255) / 256, 256, 0, stream>>>(shP4, srcP, x4, dotsP, E);
    k_hy<<<N, 128, 0, stream>>>(dotsP, lerpP, rowptr, Tp, y, N);
    {
        long long threads = (long long)N * 64;
        int blocks = (int)((threads + 255) / 256);
        k_out<<<blocks, 256, 0, stream>>>(srcP, lerpP, rowptr, y, Tp, out, N);
    }
}